// Round 4
// baseline (976.083 us; speedup 1.0000x reference)
//
#include <hip/hip_runtime.h>
#include <math.h>

// MLA + MoE block for gfx950. R8 (= R7 with the plane-overlap bug fixed):
// - gemm_sk: 128x64 tile, split-k3 (z=0 RMW into out, z=1->pC, z=2->x2; both planes
//   PROVEN dead: h2f dead after route_score, x2 dead after ln_bf_f32; R7's pB plane
//   overlapped sprojCat's tail -> NaN). sk_reduce sums the 2 planes into out.
// - everything else unchanged from R6.

#define DEV __device__ __forceinline__

typedef __attribute__((ext_vector_type(8))) short short8;
typedef __attribute__((ext_vector_type(8))) __bf16 bf16x8;
typedef __attribute__((ext_vector_type(4))) float floatx4;

DEV short f2bf(float f) {
  union { float f; unsigned u; } v; v.f = f;
  unsigned r = v.u + 0x7fffu + ((v.u >> 16) & 1u);
  return (short)(r >> 16);
}
DEV float bf2f(short s) {
  union { float f; unsigned u; } v; v.u = ((unsigned)(unsigned short)s) << 16;
  return v.f;
}
// branchless gelu: A&S 7.1.26 erf (abs err 1.5e-7, << bf16 ULP), no libm call
DEV float gelu_f(float v) {
  float z = fabsf(v) * 0.70710678118654752f;
  float t = __fdividef(1.0f, 1.0f + 0.3275911f * z);
  float poly = t * (0.254829592f + t * (-0.284496736f +
               t * (1.421413741f + t * (-1.453152027f + t * 1.061405429f))));
  float er = 1.0f - poly * __expf(-z * z);
  er = (v < 0.f) ? -er : er;
  return 0.5f * v * (1.0f + er);
}

DEV floatx4 mfma16(short8 a, short8 b, floatx4 c) {
  return __builtin_amdgcn_mfma_f32_16x16x32_bf16(
      __builtin_bit_cast(bf16x8, a), __builtin_bit_cast(bf16x8, b), c, 0, 0, 0);
}
DEV void async16(void* lds_uniform, const void* gptr) {
  __builtin_amdgcn_global_load_lds(
      (const __attribute__((address_space(1))) void*)gptr,
      (__attribute__((address_space(3))) void*)lds_uniform, 16, 0, 0);
}

// XCD-bijective tile swizzle — ONLY for fully-active grids (no early exit!).
DEV void xcd_swz(int& n0, int& m0) {
  const int NT = gridDim.x;
  const int flat = blockIdx.y * NT + blockIdx.x;
  const int nwg = NT * gridDim.y;
  const int w = (flat & 7) * (nwg >> 3) + (flat >> 3);
  n0 = (w % NT) * 128;
  m0 = (w / NT) * 128;
}

// ---------------- prep: casts ----------------

__global__ void cast2_bf4(const float4* __restrict__ srcA, short4* __restrict__ dstA,
                          const float4* __restrict__ srcB, short4* __restrict__ dstB,
                          long n4each) {
  long i = (long)blockIdx.x * blockDim.x + threadIdx.x;
  long stride = (long)gridDim.x * blockDim.x;
  for (; i < 2 * n4each; i += stride) {
    const float4* s; short4* d; long j;
    if (i < n4each) { s = srcA; d = dstA; j = i; }
    else { s = srcB; d = dstB; j = i - n4each; }
    float4 v = s[j];
    short4 o; o.x = f2bf(v.x); o.y = f2bf(v.y); o.z = f2bf(v.z); o.w = f2bf(v.w);
    d[j] = o;
  }
}

__global__ void cast_shared(const float4* __restrict__ sfc4, const float4* __restrict__ sproj4,
                            short4* __restrict__ fcCat4, short4* __restrict__ projCat4) {
  long i = (long)blockIdx.x * 256 + threadIdx.x;
  float4 v;
  if (i < 1179648) {
    v = sfc4[i];
    short4 o; o.x = f2bf(v.x); o.y = f2bf(v.y); o.z = f2bf(v.z); o.w = f2bf(v.w);
    fcCat4[i] = o;
  } else {
    long j = i - 1179648;
    long d = j / 1536, k4 = j - d * 1536;
    v = (k4 < 768) ? sproj4[d * 768 + k4] : sproj4[589824 + d * 768 + (k4 - 768)];
    short4 o; o.x = f2bf(v.x); o.y = f2bf(v.y); o.z = f2bf(v.z); o.w = f2bf(v.w);
    projCat4[j] = o;
  }
}

__global__ void cast_hl4(const float4* __restrict__ src, short4* __restrict__ dhi,
                         short4* __restrict__ dlo, long n4) {
  long i = (long)blockIdx.x * blockDim.x + threadIdx.x;
  long stride = (long)gridDim.x * blockDim.x;
  for (; i < n4; i += stride) {
    float4 v = src[i];
    short4 h, l;
    h.x = f2bf(v.x); l.x = f2bf(v.x - bf2f(h.x));
    h.y = f2bf(v.y); l.y = f2bf(v.y - bf2f(h.y));
    h.z = f2bf(v.z); l.z = f2bf(v.z - bf2f(h.z));
    h.w = f2bf(v.w); l.w = f2bf(v.w - bf2f(h.w));
    dhi[i] = h; dlo[i] = l;
  }
}

__launch_bounds__(256)
__global__ void transpose_cast_hl(const float* __restrict__ src, short* __restrict__ dhi,
                                  short* __restrict__ dlo, int K, int N) {
  __shared__ float tile[64][65];
  int k0 = blockIdx.x * 64, n0 = blockIdx.y * 64;
  for (int i = threadIdx.x; i < 4096; i += 256) {
    int r = i >> 6, c = i & 63;
    tile[r][c] = (n0 + c < N) ? src[(size_t)(k0 + r) * N + n0 + c] : 0.f;
  }
  __syncthreads();
  for (int i = threadIdx.x; i < 4096; i += 256) {
    int r = i >> 6, c = i & 63;
    float v = tile[c][r];
    short h = f2bf(v);
    dhi[(size_t)(n0 + r) * K + k0 + c] = h;
    dlo[(size_t)(n0 + r) * K + k0 + c] = f2bf(v - bf2f(h));
  }
}

// ---------------- LayerNorms ----------------

__launch_bounds__(256)
__global__ void ln_hl(const float* __restrict__ in, int ldi, int N,
                      const float* __restrict__ w, const float* __restrict__ b,
                      short* __restrict__ ohi, short* __restrict__ olo, int ldo) {
  const int row = blockIdx.x * 4 + (threadIdx.x >> 6);
  const int lane = threadIdx.x & 63;
  const float* r = in + (size_t)row * ldi;
  float s = 0.f, s2 = 0.f;
  for (int i = lane; i < N; i += 64) { float v = r[i]; s += v; s2 += v * v; }
#pragma unroll
  for (int off = 32; off >= 1; off >>= 1) { s += __shfl_xor(s, off); s2 += __shfl_xor(s2, off); }
  float mean = s / N, var = s2 / N - mean * mean;
  float rstd = rsqrtf(var + 1e-5f);
  for (int i = lane; i < N; i += 64) {
    float y = (r[i] - mean) * rstd * w[i];
    if (b) y += b[i];
    short h = f2bf(y);
    ohi[(size_t)row * ldo + i] = h;
    olo[(size_t)row * ldo + i] = f2bf(y - bf2f(h));
  }
}

__launch_bounds__(256)
__global__ void ln_qkv(const float* __restrict__ Ccat,
                       const float* __restrict__ qw, const float* __restrict__ qb,
                       const float* __restrict__ kw, const float* __restrict__ kb,
                       short* __restrict__ cqH, short* __restrict__ cqL,
                       short* __restrict__ kvH, short* __restrict__ kvL) {
  const int vrow = blockIdx.x * 4 + (threadIdx.x >> 6);
  const int lane = threadIdx.x & 63;
  const float* r; int N; const float* w; const float* b; short* oh; short* ol; int ldo; int row;
  if (vrow < 4096) {
    row = vrow; r = Ccat + (size_t)row * 928; N = 384; w = qw; b = qb; oh = cqH; ol = cqL; ldo = 384;
  } else {
    row = vrow - 4096; r = Ccat + (size_t)row * 928 + 384; N = 512; w = kw; b = kb; oh = kvH; ol = kvL; ldo = 512;
  }
  float s = 0.f, s2 = 0.f;
  for (int i = lane; i < N; i += 64) { float v = r[i]; s += v; s2 += v * v; }
#pragma unroll
  for (int off = 32; off >= 1; off >>= 1) { s += __shfl_xor(s, off); s2 += __shfl_xor(s2, off); }
  float mean = s / N, var = s2 / N - mean * mean;
  float rstd = rsqrtf(var + 1e-5f);
  for (int i = lane; i < N; i += 64) {
    float y = (r[i] - mean) * rstd * w[i] + b[i];
    short h = f2bf(y);
    oh[(size_t)row * ldo + i] = h;
    ol[(size_t)row * ldo + i] = f2bf(y - bf2f(h));
  }
}

__launch_bounds__(256)
__global__ void ln_bf_f32(const float* __restrict__ in, const float* __restrict__ w,
                          short* __restrict__ obf, float* __restrict__ of,
                          float* __restrict__ outInit) {
  const int row = blockIdx.x * 4 + (threadIdx.x >> 6);
  const int lane = threadIdx.x & 63;
  const float* r = in + (size_t)row * 768;
  float s = 0.f, s2 = 0.f;
  for (int i = lane; i < 768; i += 64) { float v = r[i]; s += v; s2 += v * v; }
#pragma unroll
  for (int off = 32; off >= 1; off >>= 1) { s += __shfl_xor(s, off); s2 += __shfl_xor(s2, off); }
  float mean = s / 768.f, var = s2 / 768.f - mean * mean;
  float rstd = rsqrtf(var + 1e-5f);
  for (int i = lane; i < 768; i += 64) {
    float xv = r[i];
    float y = (xv - mean) * rstd * w[i];
    obf[(size_t)row * 768 + i] = f2bf(y);
    of[(size_t)row * 768 + i] = y;
    outInit[(size_t)row * 768 + i] = xv;
  }
}

// ---------------- split-precision GEMM (chunk-swizzled LDS, BK=32) ----------------

template<int RESID>
__launch_bounds__(256)
__global__ void gemm3(const short* __restrict__ Ahi, const short* __restrict__ Alo, int lda,
                      const short* __restrict__ Bhi, const short* __restrict__ Blo, int ldb,
                      float* __restrict__ Cf, int ldc, const float* __restrict__ resid,
                      int M, int N, int K) {
  __shared__ __align__(16) short AsH[4096], AsL[4096], BsH[4096], BsL[4096];
  const int tid = threadIdx.x;
  int n0, m0; xcd_swz(n0, m0);
  const int wave = tid >> 6, lane = tid & 63;
  const int wm = (wave >> 1) * 64, wn = (wave & 1) * 64;
  const int lr = lane & 15, rb = (lane >> 4) * 4;
  const int stg = ((tid & 3) ^ ((tid >> 3) & 3)) * 8;
  const int lkx = (((lane >> 4) ^ ((lr >> 1) & 3))) * 8;
  const floatx4 fz = {0.f, 0.f, 0.f, 0.f};
  floatx4 acc[4][4];
#pragma unroll
  for (int i = 0; i < 4; i++)
#pragma unroll
    for (int j = 0; j < 4; j++) acc[i][j] = fz;
  const size_t rowA = (size_t)(m0 + (tid >> 2)) * lda + stg;
  const size_t rowB = (size_t)(n0 + (tid >> 2)) * ldb + stg;
  const size_t a64 = (size_t)64 * lda, b64 = (size_t)64 * ldb;
  short* AsHW = AsH + wave * 512; short* AsLW = AsL + wave * 512;
  short* BsHW = BsH + wave * 512; short* BsLW = BsL + wave * 512;
  for (int k0 = 0; k0 < K; k0 += 32) {
    async16(AsHW, Ahi + rowA + k0);        async16(AsHW + 2048, Ahi + rowA + a64 + k0);
    async16(AsLW, Alo + rowA + k0);        async16(AsLW + 2048, Alo + rowA + a64 + k0);
    async16(BsHW, Bhi + rowB + k0);        async16(BsHW + 2048, Bhi + rowB + b64 + k0);
    async16(BsLW, Blo + rowB + k0);        async16(BsLW + 2048, Blo + rowB + b64 + k0);
    __syncthreads();
    short8 ah[4], al[4], bh[4], bl[4];
#pragma unroll
    for (int i = 0; i < 4; i++) {
      ah[i] = *(const short8*)&AsH[(wm + i * 16 + lr) * 32 + lkx];
      al[i] = *(const short8*)&AsL[(wm + i * 16 + lr) * 32 + lkx];
    }
#pragma unroll
    for (int j = 0; j < 4; j++) {
      bh[j] = *(const short8*)&BsH[(wn + j * 16 + lr) * 32 + lkx];
      bl[j] = *(const short8*)&BsL[(wn + j * 16 + lr) * 32 + lkx];
    }
#pragma unroll
    for (int i = 0; i < 4; i++)
#pragma unroll
      for (int j = 0; j < 4; j++) {
        acc[i][j] = mfma16(ah[i], bh[j], acc[i][j]);
        acc[i][j] = mfma16(ah[i], bl[j], acc[i][j]);
        acc[i][j] = mfma16(al[i], bh[j], acc[i][j]);
      }
    __syncthreads();
  }
#pragma unroll
  for (int i = 0; i < 4; i++) {
    int row = m0 + wm + i * 16 + rb;
#pragma unroll
    for (int j = 0; j < 4; j++) {
      int col = n0 + wn + j * 16 + lr;
      if (col < N) {
#pragma unroll
        for (int r = 0; r < 4; r++) {
          int rr = row + r;
          if (rr < M) {
            float v = acc[i][j][r];
            if (RESID) v += resid[(size_t)rr * ldc + col];
            Cf[(size_t)rr * ldc + col] = v;
          }
        }
      }
    }
  }
}

// ---------------- plain bf16 GEMM + gelu -> bf16 out (shared fc), BK=64 ----------------

__launch_bounds__(256)
__global__ void gemm_fc(const short* __restrict__ A, int lda,
                        const short* __restrict__ Bt, int ldb,
                        short* __restrict__ Cb, int ldc, int K) {
  __shared__ __align__(16) short As[8192], Bs[8192];
  const int tid = threadIdx.x;
  int n0, m0; xcd_swz(n0, m0);
  const int wave = tid >> 6, lane = tid & 63;
  const int wm = (wave >> 1) * 64, wn = (wave & 1) * 64;
  const int lr = lane & 15, q4 = lane >> 4, rb = q4 * 4;
  const int srow = tid >> 3;
  const int sg = ((tid & 7) ^ (srow & 7)) * 8;      // staged global chunk (pre-swizzled src)
  const int cx0 = ((q4 ^ (lr & 7))) * 8;            // read swizzle, ks=0
  const int cx1 = (((4 + q4) ^ (lr & 7))) * 8;      // ks=1
  const floatx4 fz = {0.f, 0.f, 0.f, 0.f};
  floatx4 acc[4][4];
#pragma unroll
  for (int i = 0; i < 4; i++)
#pragma unroll
    for (int j = 0; j < 4; j++) acc[i][j] = fz;
  const short* Ag = A + (size_t)(m0 + srow) * lda + sg;
  const short* Bg = Bt + (size_t)(n0 + srow) * ldb + sg;
  short* AsW = As + wave * 512; short* BsW = Bs + wave * 512;
  const size_t a32 = (size_t)32 * lda, b32 = (size_t)32 * ldb;
  for (int k0 = 0; k0 < K; k0 += 64) {
    async16(AsW,        Ag + k0);            async16(AsW + 2048, Ag + a32 + k0);
    async16(AsW + 4096, Ag + 2 * a32 + k0);  async16(AsW + 6144, Ag + 3 * a32 + k0);
    async16(BsW,        Bg + k0);            async16(BsW + 2048, Bg + b32 + k0);
    async16(BsW + 4096, Bg + 2 * b32 + k0);  async16(BsW + 6144, Bg + 3 * b32 + k0);
    __syncthreads();
#pragma unroll
    for (int ks = 0; ks < 2; ks++) {
      const int cx = ks ? cx1 : cx0;
      short8 af[4], bfr[4];
#pragma unroll
      for (int i = 0; i < 4; i++) af[i] = *(const short8*)&As[(wm + i * 16 + lr) * 64 + cx];
#pragma unroll
      for (int j = 0; j < 4; j++) bfr[j] = *(const short8*)&Bs[(wn + j * 16 + lr) * 64 + cx];
#pragma unroll
      for (int i = 0; i < 4; i++)
#pragma unroll
        for (int j = 0; j < 4; j++) acc[i][j] = mfma16(af[i], bfr[j], acc[i][j]);
    }
    __syncthreads();
  }
#pragma unroll
  for (int i = 0; i < 4; i++) {
    int row = m0 + wm + i * 16 + rb;
#pragma unroll
    for (int j = 0; j < 4; j++) {
      int col = n0 + wn + j * 16 + lr;
#pragma unroll
      for (int r = 0; r < 4; r++)
        Cb[(size_t)(row + r) * ldc + col] = f2bf(gelu_f(acc[i][j][r]));
    }
  }
}

// ---------------- shared proj: 128x64 tile, split-k3, NO atomics ----------------
// z=0: plain RMW into out (sole writer). z=1 -> p1, z=2 -> p2 (plain stores).

__launch_bounds__(256)
__global__ void gemm_sk(const short* __restrict__ A, int lda,
                        const short* __restrict__ Bt, int ldb,
                        float* __restrict__ out, int ldc,
                        float* __restrict__ p1, float* __restrict__ p2, int klen) {
  __shared__ __align__(16) short As[8192], Bs[4096];
  const int tid = threadIdx.x;
  const int m0 = blockIdx.y * 128, n0 = blockIdx.x * 64;
  const int z = blockIdx.z;
  const int koff = z * klen;
  const int wave = tid >> 6, lane = tid & 63;
  const int wm = (wave >> 1) * 64, wn = (wave & 1) * 32;
  const int lr = lane & 15, q4 = lane >> 4, rb = q4 * 4;
  const int srow = tid >> 3;
  const int sg = ((tid & 7) ^ (srow & 7)) * 8;
  const int cx0 = ((q4 ^ (lr & 7))) * 8;
  const int cx1 = (((4 + q4) ^ (lr & 7))) * 8;
  const floatx4 fz = {0.f, 0.f, 0.f, 0.f};
  floatx4 acc[4][2];
#pragma unroll
  for (int i = 0; i < 4; i++)
#pragma unroll
    for (int j = 0; j < 2; j++) acc[i][j] = fz;
  const short* Ag = A + (size_t)(m0 + srow) * lda + koff + sg;
  const short* Bg = Bt + (size_t)(n0 + srow) * ldb + koff + sg;
  short* AsW = As + wave * 512; short* BsW = Bs + wave * 512;
  const size_t a32 = (size_t)32 * lda, b32 = (size_t)32 * ldb;
  for (int k0 = 0; k0 < klen; k0 += 64) {
    async16(AsW,        Ag + k0);            async16(AsW + 2048, Ag + a32 + k0);
    async16(AsW + 4096, Ag + 2 * a32 + k0);  async16(AsW + 6144, Ag + 3 * a32 + k0);
    async16(BsW,        Bg + k0);            async16(BsW + 2048, Bg + b32 + k0);
    __syncthreads();
#pragma unroll
    for (int ks = 0; ks < 2; ks++) {
      const int cx = ks ? cx1 : cx0;
      short8 af[4], bfr[2];
#pragma unroll
      for (int i = 0; i < 4; i++) af[i] = *(const short8*)&As[(wm + i * 16 + lr) * 64 + cx];
#pragma unroll
      for (int j = 0; j < 2; j++) bfr[j] = *(const short8*)&Bs[(wn + j * 16 + lr) * 64 + cx];
#pragma unroll
      for (int i = 0; i < 4; i++)
#pragma unroll
        for (int j = 0; j < 2; j++) acc[i][j] = mfma16(af[i], bfr[j], acc[i][j]);
    }
    __syncthreads();
  }
  float* dst = (z == 0) ? out : (z == 1 ? p1 : p2);
#pragma unroll
  for (int i = 0; i < 4; i++) {
    int row = m0 + wm + i * 16 + rb;
#pragma unroll
    for (int j = 0; j < 2; j++) {
      int col = n0 + wn + j * 16 + lr;
#pragma unroll
      for (int r = 0; r < 4; r++) {
        size_t idx = (size_t)(row + r) * ldc + col;
        if (z == 0) dst[idx] += acc[i][j][r];
        else dst[idx] = acc[i][j][r];
      }
    }
  }
}

__global__ void sk_reduce(float4* __restrict__ out, const float4* __restrict__ p1,
                          const float4* __restrict__ p2) {
  int i = blockIdx.x * 256 + threadIdx.x;
  const int stride = gridDim.x * 256;
  for (; i < 786432; i += stride) {
    float4 o = out[i], a = p1[i], b = p2[i];
    o.x += a.x + b.x;
    o.y += a.y + b.y;
    o.z += a.z + b.z;
    o.w += a.w + b.w;
    out[i] = o;
  }
}

// ---------------- RoPE builders (hi/lo) ----------------

__global__ void build_qk(const float* __restrict__ Qf, const float* __restrict__ KVf,
                         const float* __restrict__ Ccat,
                         short* __restrict__ qh, short* __restrict__ ql,
                         short* __restrict__ kh, short* __restrict__ kl) {
  int id = blockIdx.x * blockDim.x + threadIdx.x;
  if (id >= 4096 * 12) return;
  int token = id / 12, hh_ = id - token * 12;
  int s = token & 1023, b = token >> 10;
  size_t base = ((size_t)(b * 12 + hh_) * 1024 + s) * 64;
  float vals[64];
  if (blockIdx.y == 0) {
    const float* q = Qf + (size_t)token * 768 + hh_ * 64;
#pragma unroll
    for (int d = 0; d < 32; d++) vals[d] = q[d];
#pragma unroll
    for (int i = 0; i < 16; i++) {
      float fi = powf(10000.f, -(float)(2 * i) / 64.f);
      float sn, cs; sincosf((float)s * fi, &sn, &cs);
      vals[32 + i] = q[32 + i] * cs - q[48 + i] * sn;
      vals[48 + i] = q[48 + i] * cs + q[32 + i] * sn;
    }
#pragma unroll
    for (int d = 0; d < 64; d++) {
      short h = f2bf(vals[d]);
      qh[base + d] = h; ql[base + d] = f2bf(vals[d] - bf2f(h));
    }
  } else {
    const float* kv = KVf + (size_t)token * 1152 + hh_ * 96;
#pragma unroll
    for (int d = 0; d < 32; d++) vals[d] = kv[d];
    const float* kr = Ccat + (size_t)token * 928 + 896;
#pragma unroll
    for (int i = 0; i < 16; i++) {
      float fi = powf(10000.f, -(float)(2 * i) / 64.f);
      float sn, cs; sincosf((float)s * fi, &sn, &cs);
      vals[32 + i] = kr[i] * cs - kr[16 + i] * sn;
      vals[48 + i] = kr[16 + i] * cs + kr[i] * sn;
    }
#pragma unroll
    for (int d = 0; d < 64; d++) {
      short h = f2bf(vals[d]);
      kh[base + d] = h; kl[base + d] = f2bf(vals[d] - bf2f(h));
    }
  }
}

__launch_bounds__(256)
__global__ void build_vt_hl(const float* __restrict__ KVf,
                            short* __restrict__ vth, short* __restrict__ vtl) {
  __shared__ float tile[64][65];
  const int s0 = blockIdx.x * 64, bh = blockIdx.y;
  const int b = bh / 12, h = bh - b * 12;
  for (int i = threadIdx.x; i < 4096; i += 256) {
    int tl = i >> 6, d = i & 63;
    int token = b * 1024 + s0 + tl;
    tile[tl][d] = KVf[(size_t)token * 1152 + h * 96 + 32 + d];
  }
  __syncthreads();
  for (int i = threadIdx.x; i < 4096; i += 256) {
    int d = i >> 6, sl = i & 63;
    float v = tile[sl][d];
    short hh = f2bf(v);
    size_t idx = (size_t)bh * 65536 + (size_t)d * 1024 + s0 + sl;
    vth[idx] = hh;
    vtl[idx] = f2bf(v - bf2f(hh));
  }
}

// ---------------- flash attention (swizzled, padded P, paired q-tiles) ----------------

__launch_bounds__(256)
__global__ void attn3(const short* __restrict__ qbh, const short* __restrict__ qbl,
                      const short* __restrict__ kbh, const short* __restrict__ kbl,
                      const short* __restrict__ vth, const short* __restrict__ vtl,
                      short* __restrict__ obh, short* __restrict__ obl) {
  const int bh = blockIdx.y;
  const int b = bh / 12, h = bh - b * 12;
  const short* Qh = qbh + (size_t)bh * 65536;
  const short* Ql = qbl + (size_t)bh * 65536;
  const short* Kh = kbh + (size_t)bh * 65536;
  const short* Kl = kbl + (size_t)bh * 65536;
  const short* Vh = vth + (size_t)bh * 65536;
  const short* Vl = vtl + (size_t)bh * 65536;
  __shared__ __align__(16) short KsH[4096], KsL[4096], VsH[4096], VsL[4096];
  __shared__ __align__(16) short PsH[4608], PsL[4608];
  const int tid = threadIdx.x, wave = tid >> 6, lane = tid & 63;
  const int lr = lane & 15, q4 = lane >> 4, lk = (lane >> 4) * 8;
  const int sx0 = ((q4 ^ (lr & 7))) * 8;
  const int sx1 = (((4 + q4) ^ (lr & 7))) * 8;
  const int soff_sw = (((tid & 7) ^ ((tid >> 3) & 7))) * 8;
  const int srow = tid >> 3;
  short* KsHW = KsH + wave * 512; short* KsLW = KsL + wave * 512;
  short* VsHW = VsH + wave * 512; short* VsLW = VsL + wave * 512;
  short* myPh = PsH + wave * 1152; short* myPl = PsL + wave * 1152;
  const floatx4 fz = {0.f, 0.f, 0.f, 0.f};
#pragma unroll
  for (int ph = 0; ph < 2; ph++) {
    const int qt = ph ? 15 - blockIdx.x : blockIdx.x;
    const int qrow0 = qt * 64 + wave * 16;
    short8 qfh[2], qfl[2];
    qfh[0] = *(const short8*)&Qh[(size_t)(qrow0 + lr) * 64 + lk];
    qfh[1] = *(const short8*)&Qh[(size_t)(qrow0 + lr) * 64 + 32 + lk];
    qfl[0] = *(const short8*)&Ql[(size_t)(qrow0 + lr) * 64 + lk];
    qfl[1] = *(const short8*)&Ql[(size_t)(qrow0 + lr) * 64 + 32 + lk];
    floatx4 oacc[4];
#pragma unroll
    for (int t = 0; t < 4; t++) oacc[t] = fz;
    float m_i[4], l_i[4];
#pragma unroll
    for (int r = 0; r < 4; r++) { m_i[r] = -__builtin_inff(); l_i[r] = 0.f; }
    for (int kt = 0; kt <= qt; kt++) {
      __syncthreads();
      size_t krow = (size_t)(kt * 64 + srow) * 64 + soff_sw;
      size_t vrow = (size_t)srow * 1024 + kt * 64 + soff_sw;
      async16(KsHW, Kh + krow);        async16(KsHW + 2048, Kh + krow + 32 * 64);
      async16(KsLW, Kl + krow);        async16(KsLW + 2048, Kl + krow + 32 * 64);
      async16(VsHW, Vh + vrow);        async16(VsHW + 2048, Vh + vrow + 32 * 1024);
      async16(VsLW, Vl + vrow);        async16(VsLW + 2048, Vl + vrow + 32 * 1024);
      __syncthreads();
      floatx4 sacc[4];
#pragma unroll
      for (int j = 0; j < 4; j++) sacc[j] = fz;
#pragma unroll
      for (int j = 0; j < 4; j++) {
        int rbase = (j * 16 + lr) * 64;
        short8 kh0 = *(const short8*)&KsH[rbase + sx0];
        short8 kh1 = *(const short8*)&KsH[rbase + sx1];
        short8 kl0 = *(const short8*)&KsL[rbase + sx0];
        short8 kl1 = *(const short8*)&KsL[rbase + sx1];
        sacc[j] = mfma16(qfh[0], kh0, sacc[j]);
        sacc[j] = mfma16(qfh[1], kh1, sacc[j]);
        sacc[j] = mfma16(qfh[0], kl0, sacc[j]);
        sacc[j] = mfma16(qfh[1], kl1, sacc[j]);
        sacc[j] = mfma16(qfl[0], kh0, sacc[j]);
        sacc[j] = mfma16(qfl[1], kh1, sacc[j]);
      }
      float pv[4][4], mrow[4];
#pragma unroll
      for (int r = 0; r < 4; r++) mrow[r] = -__builtin_inff();
      const bool diag = (kt == qt);
#pragma unroll
      for (int j = 0; j < 4; j++)
#pragma unroll
        for (int r = 0; r < 4; r++) {
          float v = sacc[j][r] * 0.125f;
          if (diag) {
            int qg = qrow0 + q4 * 4 + r;
            int kg = kt * 64 + j * 16 + lr;
            if (kg > qg) v = -__builtin_inff();
          }
          pv[j][r] = v;
          mrow[r] = fmaxf(mrow[r], v);
        }
#pragma unroll
      for (int r = 0; r < 4; r++)
#pragma unroll
        for (int off = 1; off < 16; off <<= 1) mrow[r] = fmaxf(mrow[r], __shfl_xor(mrow[r], off));
      float alpha[4], rsum[4];
#pragma unroll
      for (int r = 0; r < 4; r++) {
        float nm = fmaxf(m_i[r], mrow[r]);
        alpha[r] = __expf(m_i[r] - nm);
        m_i[r] = nm; rsum[r] = 0.f;
      }
#pragma unroll
      for (int j = 0; j < 4; j++)
#pragma unroll
        for (int r = 0; r < 4; r++) {
          float pe = __expf(pv[j][r] - m_i[r]);
          pv[j][r] = pe; rsum[r] += pe;
        }
#pragma unroll
      for (int r = 0; r < 4; r++) {
#pragma unroll
        for (int off = 1; off < 16; off <<= 1) rsum[r] += __shfl_xor(rsum[r], off);
        l_i[r] = l_i[r] * alpha[r] + rsum[r];
      }
#pragma unroll
      for (int t = 0; t < 4; t++)
#pragma unroll
        for (int r = 0; r < 4; r++) oacc[t][r] *= alpha[r];
#pragma unroll
      for (int j = 0; j < 4; j++)
#pragma unroll
        for (int r = 0; r < 4; r++) {
          float p = pv[j][r];
          short hh = f2bf(p);
          myPh[(q4 * 4 + r) * 72 + j * 16 + lr] = hh;
          myPl[(q4 * 4 + r) * 72 + j * 16 + lr] = f2bf(p - bf2f(hh));
        }
      __asm__ volatile("s_waitcnt lgkmcnt(0)" ::: "memory");
#pragma unroll
      for (int c = 0; c < 2; c++) {
        short8 ph_ = *(const short8*)&myPh[lr * 72 + c * 32 + lk];
        short8 pl_ = *(const short8*)&myPl[lr * 72 + c * 32 + lk];
        const int sxc = c ? sx1 : sx0;
#pragma unroll
        for (int t = 0; t < 4; t++) {
          int rbase = (t * 16 + lr) * 64;
          short8 vh = *(const short8*)&VsH[rbase + sxc];
          short8 vl = *(const short8*)&VsL[rbase + sxc];
          oacc[t] = mfma16(ph_, vh, oacc[t]);
          oacc[t] = mfma16(ph_, vl, oacc[t]);
          oacc[t] = mfma16(pl_, vh, oacc[t]);
        }
      }
    }
#pragma unroll
    for (int t = 0; t < 4; t++)
#pragma unroll
      for (int r = 0; r < 4; r++) {
        int s = qrow0 + q4 * 4 + r;
        int token = b * 1024 + s;
        float ov = oacc[t][r] / l_i[r];
        short hh = f2bf(ov);
        size_t idx = (size_t)token * 768 + h * 64 + t * 16 + lr;
        obh[idx] = hh;
        obl[idx] = f2bf(ov - bf2f(hh));
      }
  }
}

// ---------------- routing ----------------

__launch_bounds__(256)
__global__ void route_score(const float* __restrict__ h2f, const float* __restrict__ cent,
                            const float* __restrict__ rbias,
                            int* __restrict__ topexp, float* __restrict__ gates) {
  const int token = blockIdx.x * 4 + (threadIdx.x >> 6);
  const int lane = threadIdx.x & 63;
  const float* hv = h2f + (size_t)token * 768;
  float hreg[12];
#pragma unroll
  for (int ii = 0; ii < 12; ii++) hreg[ii] = hv[lane + 64 * ii];
  float raw[8];
#pragma unroll
  for (int e = 0; e < 8; e++) {
    const float* cv = cent + e * 768;
    float p = 0.f;
#pragma unroll
    for (int ii = 0; ii < 12; ii++) p += hreg[ii] * cv[lane + 64 * ii];
#pragma unroll
    for (int off = 32; off >= 1; off >>= 1) p += __shfl_xor(p, off);
    raw[e] = p;
  }
  if (lane == 0) {
    float b0 = -__builtin_inff(); int i1 = 0;
#pragma unroll
    for (int e = 0; e < 8; e++) { float be = raw[e] + rbias[e]; if (be > b0) { b0 = be; i1 = e; } }
    float b1 = -__builtin_inff(); int i2 = 0;
#pragma unroll
    for (int e = 0; e < 8; e++) {
      if (e == i1) continue;
      float be = raw[e] + rbias[e];
      if (be > b1) { b1 = be; i2 = e; }
    }
    float w1 = 1.f / (1.f + expf(-raw[i1]));
    float w2 = 1.f / (1.f + expf(-raw[i2]));
    float wsum = w1 + w2 + 1e-9f;
    topexp[token] = i1;        gates[token] = w1 / wsum;
    topexp[4096 + token] = i2; gates[4096 + token] = w2 / wsum;
  }
}

__launch_bounds__(256)
__global__ void build_lists(const int* __restrict__ topexp,
                            int* __restrict__ counts, int* __restrict__ lists) {
  const int e = blockIdx.x;
  __shared__ int wave_off[4];
  const int wave = threadIdx.x >> 6, lane = threadIdx.x & 63;
  int total = 0;
  for (int c0 = 0; c0 < 8192; c0 += 256) {
    int slot = c0 + threadIdx.x;
    bool m = (topexp[slot] == e);
    unsigned long long bal = __ballot(m);
    int wcnt = __popcll(bal);
    int lpre = __popcll(bal & ((1ull << lane) - 1ull));
    if (lane == 0) wave_off[wave] = wcnt;
    __syncthreads();
    int woff = 0;
#pragma unroll
    for (int w = 0; w < 4; w++) if (w < wave) woff += wave_off[w];
    int chunk_total = wave_off[0] + wave_off[1] + wave_off[2] + wave_off[3];
    if (m) lists[e * 4096 + total + woff + lpre] = slot;
    total += chunk_total;
    __syncthreads();
  }
  if (threadIdx.x == 0) counts[e] = total;
}

// ---------------- z-batched expert GEMMs (BK=64, direct mapping) ----------------

__launch_bounds__(256)
__global__ void expert_fc_z(const short* __restrict__ h2bf, const short* __restrict__ wfc,
                            const int* __restrict__ lists, const int* __restrict__ counts,
                            int ebase, short* __restrict__ act) {
  const int lz = blockIdx.z, e = ebase + lz;
  const int cnt = counts[e];
  const int m0 = blockIdx.y * 128;
  if (m0 >= cnt) return;
  const int n0 = blockIdx.x * 128;
  int aoff = 0;
  for (int i = 0; i < lz; i++) aoff += counts[ebase + i];
  __shared__ __align__(16) short As[8192], Bs[8192];
  __shared__ int slots[128];
  const int tid = threadIdx.x;
  if (tid < 128) slots[tid] = lists[e * 4096 + m0 + tid];
  __syncthreads();
  const int wave = tid >> 6, lane = tid & 63;
  const int wm = (wave >> 1) * 64, wn = (wave & 1) * 64;
  const int lr = lane & 15, q4 = lane >> 4, rb = q4 * 4;
  const int srow = tid >> 3;
  const int sg = ((tid & 7) ^ (srow & 7)) * 8;
  const int cx0 = ((q4 ^ (lr & 7))) * 8;
  const int cx1 = (((4 + q4) ^ (lr & 7))) * 8;
  int tok[4];
#pragma unroll
  for (int p = 0; p < 4; p++) tok[p] = slots[p * 32 + srow] & 4095;
  const floatx4 fz = {0.f, 0.f, 0.f, 0.f};
  floatx4 acc[4][4];
#pragma unroll
  for (int i = 0; i < 4; i++)
#pragma unroll
    for (int j = 0; j < 4; j++) acc[i][j] = fz;
  const short* Ag0 = h2bf + (size_t)tok[0] * 768 + sg;
  const short* Ag1 = h2bf + (size_t)tok[1] * 768 + sg;
  const short* Ag2 = h2bf + (size_t)tok[2] * 768 + sg;
  const short* Ag3 = h2bf + (size_t)tok[3] * 768 + sg;
  const short* Bg = wfc + (size_t)lz * (3072 * 768) + (size_t)(n0 + srow) * 768 + sg;
  short* AsW = As + wave * 512; short* BsW = Bs + wave * 512;
  const size_t b32 = (size_t)32 * 768;
  for (int k0 = 0; k0 < 768; k0 += 64) {
    async16(AsW,        Ag0 + k0);           async16(AsW + 2048, Ag1 + k0);
    async16(AsW + 4096, Ag2 + k0);           async16(AsW + 6144, Ag3 + k0);
    async16(BsW,        Bg + k0);            async16(BsW + 2048, Bg + b32 + k0);
    async16(BsW + 4096, Bg + 2 * b32 + k0);  async16(BsW + 6144, Bg + 3 * b32 + k0);
    __syncthreads();
#pragma unroll
    for (int ks = 0; ks < 2; ks++) {
      const int cx = ks ? cx1 : cx0;
      short8 af[4], bfr[4];
#pragma unroll
      for (int i = 0; i < 4; i++) af[i] = *(const short8*)&As[(wm + i * 16 + lr) * 64 + cx];
#pragma unroll
      for (int j = 0; j < 4; j++) bfr[j] = *(const short8*)&Bs[(wn + j * 16 + lr) * 64 + cx];
#pragma unroll
      for (int i = 0; i < 4; i++)
#pragma unroll
        for (int j = 0; j < 4; j++) acc[i][j] = mfma16(af[i], bfr[j], acc[i][j]);
    }
    __syncthreads();
  }
#pragma unroll
  for (int i = 0; i < 4; i++) {
    int lrow = wm + i * 16 + rb;
#pragma unroll
    for (int j = 0; j < 4; j++) {
      int col = n0 + wn + j * 16 + lr;
#pragma unroll
      for (int r = 0; r < 4; r++) {
        if (m0 + lrow + r < cnt)
          act[(size_t)(aoff + m0 + lrow + r) * 3072 + col] = f2bf(gelu_f(acc[i][j][r]));
      }
    }
  }
}

__launch_bounds__(256)
__global__ void expert_proj_z(const short* __restrict__ act, const short* __restrict__ wproj,
                              const int* __restrict__ lists, const int* __restrict__ counts,
                              int ebase, const float* __restrict__ gates,
                              float* __restrict__ out) {
  const int lz = blockIdx.z >> 2, kh = blockIdx.z & 3, e = ebase + lz;
  const int cnt = counts[e];
  const int m0 = blockIdx.y * 128;
  if (m0 >= cnt) return;
  const int n0 = blockIdx.x * 128;
  int aoff = 0;
  for (int i = 0; i < lz; i++) aoff += counts[ebase + i];
  const int koff = kh * 768;
  __shared__ __align__(16) short As[8192], Bs[8192];
  __shared__ int slots[128];
  const int tid = threadIdx.x;
  if (tid < 128) slots[tid] = lists[e * 4096 + m0 + tid];
  __syncthreads();
  const int wave = tid >> 6, lane = tid & 63;
  const int wm = (wave >> 1) * 64, wn = (wave & 1) * 64;
  const int lr = lane & 15, q4 = lane >> 4, rb = q4 * 4;
  const int srow = tid >> 3;
  const int sg = ((tid & 7) ^ (srow & 7)) * 8;
  const int cx0 = ((q4 ^ (lr & 7))) * 8;
  const int cx1 = (((4 + q4) ^ (lr & 7))) * 8;
  const floatx4 fz = {0.f, 0.f, 0.f, 0.f};
  floatx4 acc[4][4];
#pragma unroll
  for (int i = 0; i < 4; i++)
#pragma unroll
    for (int j = 0; j < 4; j++) acc[i][j] = fz;
  const short* Ag = act + (size_t)(aoff + m0 + srow) * 3072 + koff + sg;
  const short* Bg = wproj + (size_t)lz * (768 * 3072) + (size_t)(n0 + srow) * 3072 + koff + sg;
  short* AsW = As + wave * 512; short* BsW = Bs + wave * 512;
  const size_t s32 = (size_t)32 * 3072;
  for (int k0 = 0; k0 < 768; k0 += 64) {
    async16(AsW,        Ag + k0);            async16(AsW + 2048, Ag + s32 + k0);
    async16(AsW + 4096, Ag + 2 * s32 + k0);  async16(AsW + 6144, Ag + 3 * s32 + k0);
    async16(BsW,        Bg + k0);            async16(BsW + 2048, Bg + s32 + k0);
    async16(BsW + 4096, Bg + 2 * s32 + k0);  async16(BsW + 6144, Bg + 3 * s32 + k0);
    __syncthreads();
#pragma unroll
    for (int ks = 0; ks < 2; ks++) {
      const int cx = ks ? cx1 : cx0;
      short8 af[4], bfr[4];
#pragma unroll
      for (int i = 0; i < 4; i++) af[i] = *(const short8*)&As[(wm + i * 16 + lr) * 64 + cx];
#pragma unroll
      for (int j = 0; j < 4; j++) bfr[j] = *(const short8*)&Bs[(wn + j * 16 + lr) * 64 + cx];
#pragma unroll
      for (int i = 0; i < 4; i++)
#pragma unroll
        for (int j = 0; j < 4; j++) acc[i][j] = mfma16(af[i], bfr[j], acc[i][j]);
    }
    __syncthreads();
  }
#pragma unroll
  for (int i = 0; i < 4; i++) {
    int lrow = wm + i * 16 + rb;
#pragma unroll
    for (int j = 0; j < 4; j++) {
      int col = n0 + wn + j * 16 + lr;
#pragma unroll
      for (int r = 0; r < 4; r++) {
        if (m0 + lrow + r < cnt) {
          int slot = slots[lrow + r];
          int token = slot & 4095;
          atomicAdd(&out[(size_t)token * 768 + col], gates[slot] * acc[i][j][r]);
        }
      }
    }
  }
}

__global__ void bad_kernel(float* out) { out[threadIdx.x] = 1e30f; }

// ---------------- launch ----------------

extern "C" void kernel_launch(void* const* d_in, const int* in_sizes, int n_in,
                              void* d_out, int out_size, void* d_ws, size_t ws_size,
                              hipStream_t stream) {
  const float* x = (const float*)d_in[0];
  const float* ln1_w = (const float*)d_in[1];
  const float* ln2_w = (const float*)d_in[2];
  const float* W_dq = (const float*)d_in[3];
  const float* W_uq = (const float*)d_in[4];
  const float* q_ln_w = (const float*)d_in[5];
  const float* q_ln_b = (const float*)d_in[6];
  const float* W_dkv = (const float*)d_in[7];
  const float* W_ukv = (const float*)d_in[8];
  const float* kv_ln_w = (const float*)d_in[9];
  const float* kv_ln_b = (const float*)d_in[10];
  const float* W_o = (const float*)d_in[11];
  const float* s_fc = (const float*)d_in[12];
  const float* s_proj = (const float*)d_in[13];
  const float* e_fc = (const float*)d_in[14];
  const float* e_proj = (const float*)d_in[15];
  const float* cent = (const float*)d_in[16];
  const float* rbias = (const float*)d_in[17];
  float* out = (float*)d_out;

  char* base = (char*)d_ws;
  size_t off = 0;
  auto take = [&](size_t bytes) -> char* {
    char* r = base + off;
    off = (off + bytes + 255) & ~(size_t)255;
    return r;
  };
  short* WcatH = (short*)take(1572864);  short* WcatL = (short*)take(1572864);
  short* WuqH  = (short*)take(589824);   short* WuqL  = (short*)take(589824);
  short* WukvH = (short*)take(1179648);  short* WukvL = (short*)take(1179648);
  short* WoH   = (short*)take(1179648);  short* WoL   = (short*)take(1179648);
  float* x2    = (float*)take(12582912);
  float* gates = (float*)take(32768);
  int*   counts= (int*)take(32);
  int*   lists = (int*)take(131072);
  int*   topexp= (int*)take(32768);
  const size_t PLANE = 6291456;
  char* pool = take(4 * 2 * PLANE);        // 50.33 MB, pA..pD contiguous
  char* R    = take(51118080);             // 50.33 MB + 128-row pad
  size_t used = off;
  if (used > ws_size) { bad_kernel<<<1, 256, 0, stream>>>(out); return; }
  char* pA = pool;
  char* pB = pool + 2 * PLANE;
  char* pC = pool + 4 * PLANE;
  char* pD = pool + 6 * PLANE;

  // phase A overlays
  short* hH   = (short*)pA;            short* hL   = (short*)(pA + PLANE);
  float* Ccat = (float*)R;                                   // 4096x928 f32 (15.2 MB)
  short* cqH  = (short*)pB;            short* cqL  = (short*)(pB + 3145728);
  short* kvlH = (short*)pD;            short* kvlL = (short*)(pD + 4194304);
  float* Qf   = (float*)pC;
  float* KVf  = (float*)(R + 15204352);                      // 4096x1152 f32 (18.9 MB)
  short* qbH  = (short*)pD;            short* qbL  = (short*)(pD + PLANE);
  short* kbH  = (short*)pA;            short* kbL  = (short*)(pA + PLANE);
  short* vtH  = (short*)pB;            short* vtL  = (short*)(pB + PLANE);
  short* obH  = (short*)pC;            short* obL  = (short*)(pC + PLANE);
  // phase B overlays
  short* h2bf    = (short*)(pD + PLANE);
  float* h2f     = (float*)pC;
  short* sfcCat  = (short*)pA;                               // 6144x768 bf16 (9.4 MB)
  short* sprojCat= (short*)(pA + 9437184);                   // 768x6144 bf16 (ends at pA+18.87MB, in pB!)
  short* actCat  = (short*)R;                                // 4096x6144 bf16 (50.3 MB)
  short* efcHalf = (short*)pA;                               // 4x(3072x768) bf16 (18.9 MB)
  short* eprojHalf=(short*)(pA + 18874368);                  // 4x(768x3072) bf16
  short* eact    = (short*)R;                                // up to 8192+128 rows x 3072
  // gemm_sk partial planes — PROVEN dead at gemm_sk time (NOT pB: sprojCat tail lives there)
  float* skP1 = (float*)pC;            // h2f dead after route_score
  float* skP2 = x2;                    // x2 dead after ln_bf_f32

  // ---- weight prep ----
  cast_hl4<<<576, 256, 0, stream>>>((const float4*)W_o, (short4*)WoH, (short4*)WoL, 147456);
  transpose_cast_hl<<<dim3(12, 6), 256, 0, stream>>>(W_dq, WcatH, WcatL, 768, 384);
  transpose_cast_hl<<<dim3(12, 10), 256, 0, stream>>>(W_dkv, WcatH + (size_t)384 * 768,
                                                      WcatL + (size_t)384 * 768, 768, 544);
  transpose_cast_hl<<<dim3(6, 12), 256, 0, stream>>>(W_uq, WuqH, WuqL, 384, 768);
  transpose_cast_hl<<<dim3(8, 18), 256, 0, stream>>>(W_ukv, WukvH, WukvL, 512, 1152);

  // ---- phase A ----
  ln_hl<<<1024, 256, 0, stream>>>(x, 768, 768, ln1_w, nullptr, hH, hL, 768);
  gemm3<0><<<dim3(8, 32), 256, 0, stream>>>(hH, hL, 768, WcatH, WcatL, 768, Ccat, 928, nullptr, 4096, 928, 768);
  ln_qkv<<<2048, 256, 0, stream>>>(Ccat, q_ln_w, q_ln_b, kv_ln_w, kv_ln_b, cqH, cqL, kvlH, kvlL);
  gemm3<0><<<dim3(6, 32), 256, 0, stream>>>(cqH, cqL, 384, WuqH, WuqL, 384, Qf, 768, nullptr, 4096, 768, 384);
  gemm3<0><<<dim3(9, 32), 256, 0, stream>>>(kvlH, kvlL, 512, WukvH, WukvL, 512, KVf, 1152, nullptr, 4096, 1152, 512);
  build_qk<<<dim3(192, 2), 256, 0, stream>>>(Qf, KVf, Ccat, qbH, qbL, kbH, kbL);
  build_vt_hl<<<dim3(16, 48), 256, 0, stream>>>(KVf, vtH, vtL);
  attn3<<<dim3(8, 48), 256, 0, stream>>>(qbH, qbL, kbH, kbL, vtH, vtL, obH, obL);
  gemm3<1><<<dim3(6, 32), 256, 0, stream>>>(obH, obL, 768, WoH, WoL, 768, x2, 768, x, 4096, 768, 768);

  // ---- phase B ----
  ln_bf_f32<<<1024, 256, 0, stream>>>(x2, ln2_w, h2bf, h2f, out);
  route_score<<<1024, 256, 0, stream>>>(h2f, cent, rbias, topexp, gates);
  build_lists<<<8, 256, 0, stream>>>(topexp, counts, lists);

  // shared experts (concat): fc -> gelu -> actCat ; proj split-k3 (planes) + reduce
  cast_shared<<<9216, 256, 0, stream>>>((const float4*)s_fc, (const float4*)s_proj,
                                        (short4*)sfcCat, (short4*)sprojCat);
  gemm_fc<<<dim3(48, 32), 256, 0, stream>>>(h2bf, 768, sfcCat, 768, actCat, 6144, 768);
  gemm_sk<<<dim3(12, 32, 3), 256, 0, stream>>>(actCat, 6144, sprojCat, 6144, out, 768,
                                               skP1, skP2, 2048);
  sk_reduce<<<1536, 256, 0, stream>>>((float4*)out, (const float4*)skP1, (const float4*)skP2);

  // routed experts: two halves of 4, z-batched
  for (int h = 0; h < 2; h++) {
    cast2_bf4<<<2048, 256, 0, stream>>>(
        (const float4*)(e_fc + (size_t)h * 4 * 3072 * 768), (short4*)efcHalf,
        (const float4*)(e_proj + (size_t)h * 4 * 768 * 3072), (short4*)eprojHalf, 2359296);
    expert_fc_z<<<dim3(24, 32, 4), 256, 0, stream>>>(h2bf, efcHalf, lists, counts, h * 4, eact);
    expert_proj_z<<<dim3(6, 32, 16), 256, 0, stream>>>(eact, eprojHalf, lists, counts, h * 4, gates, out);
  }
}

// Round 5
// 893.182 us; speedup vs baseline: 1.0928x; 1.0928x over previous
//
#include <hip/hip_runtime.h>
#include <math.h>

// MLA + MoE block for gfx950. R9:
// - routed experts restructured: single 8-expert launches (no halves); e = flatBlockId&7
//   maps one expert per XCD (A-panel + weights L2-resident, fetched once).
// - expert_proj_one: NO split-k (48 K-iters/block), NO atomics — plain bf16 stores into
//   slot-indexed routed[8192x768] plane (=x2), then gather_routed: out[t] += g1*r[t]+g2*r[4096+t].
// - expert_fc_z: all 8 experts one launch, same e=xcd swizzle.
// - dense GEMMs / attn / LN / shared experts unchanged from R8.

#define DEV __device__ __forceinline__

typedef __attribute__((ext_vector_type(8))) short short8;
typedef __attribute__((ext_vector_type(8))) __bf16 bf16x8;
typedef __attribute__((ext_vector_type(4))) float floatx4;

DEV short f2bf(float f) {
  union { float f; unsigned u; } v; v.f = f;
  unsigned r = v.u + 0x7fffu + ((v.u >> 16) & 1u);
  return (short)(r >> 16);
}
DEV float bf2f(short s) {
  union { float f; unsigned u; } v; v.u = ((unsigned)(unsigned short)s) << 16;
  return v.f;
}
// branchless gelu: A&S 7.1.26 erf (abs err 1.5e-7, << bf16 ULP), no libm call
DEV float gelu_f(float v) {
  float z = fabsf(v) * 0.70710678118654752f;
  float t = __fdividef(1.0f, 1.0f + 0.3275911f * z);
  float poly = t * (0.254829592f + t * (-0.284496736f +
               t * (1.421413741f + t * (-1.453152027f + t * 1.061405429f))));
  float er = 1.0f - poly * __expf(-z * z);
  er = (v < 0.f) ? -er : er;
  return 0.5f * v * (1.0f + er);
}

DEV floatx4 mfma16(short8 a, short8 b, floatx4 c) {
  return __builtin_amdgcn_mfma_f32_16x16x32_bf16(
      __builtin_bit_cast(bf16x8, a), __builtin_bit_cast(bf16x8, b), c, 0, 0, 0);
}
DEV void async16(void* lds_uniform, const void* gptr) {
  __builtin_amdgcn_global_load_lds(
      (const __attribute__((address_space(1))) void*)gptr,
      (__attribute__((address_space(3))) void*)lds_uniform, 16, 0, 0);
}

// XCD-bijective tile swizzle — ONLY for fully-active grids (no early exit!).
DEV void xcd_swz(int& n0, int& m0) {
  const int NT = gridDim.x;
  const int flat = blockIdx.y * NT + blockIdx.x;
  const int nwg = NT * gridDim.y;
  const int w = (flat & 7) * (nwg >> 3) + (flat >> 3);
  n0 = (w % NT) * 128;
  m0 = (w / NT) * 128;
}

// expert-per-XCD swizzle: e = flat&7 (8 experts <-> 8 XCDs), panel-local n/m.
DEV void eswz(int BN, int& e, int& m0, int& n0) {
  const int flat = (blockIdx.z * gridDim.y + blockIdx.y) * gridDim.x + blockIdx.x;
  e = flat & 7;
  const int s = flat >> 3;
  m0 = (s & 31) * 128;
  n0 = (s >> 5) * BN;
}

// ---------------- prep: casts ----------------

__global__ void cast_bf(const float4* __restrict__ src, short4* __restrict__ dst, long n4) {
  long i = (long)blockIdx.x * blockDim.x + threadIdx.x;
  long stride = (long)gridDim.x * blockDim.x;
  for (; i < n4; i += stride) {
    float4 v = src[i];
    short4 o; o.x = f2bf(v.x); o.y = f2bf(v.y); o.z = f2bf(v.z); o.w = f2bf(v.w);
    dst[i] = o;
  }
}

__global__ void cast_shared(const float4* __restrict__ sfc4, const float4* __restrict__ sproj4,
                            short4* __restrict__ fcCat4, short4* __restrict__ projCat4) {
  long i = (long)blockIdx.x * 256 + threadIdx.x;
  float4 v;
  if (i < 1179648) {
    v = sfc4[i];
    short4 o; o.x = f2bf(v.x); o.y = f2bf(v.y); o.z = f2bf(v.z); o.w = f2bf(v.w);
    fcCat4[i] = o;
  } else {
    long j = i - 1179648;
    long d = j / 1536, k4 = j - d * 1536;
    v = (k4 < 768) ? sproj4[d * 768 + k4] : sproj4[589824 + d * 768 + (k4 - 768)];
    short4 o; o.x = f2bf(v.x); o.y = f2bf(v.y); o.z = f2bf(v.z); o.w = f2bf(v.w);
    projCat4[j] = o;
  }
}

__global__ void cast_hl4(const float4* __restrict__ src, short4* __restrict__ dhi,
                         short4* __restrict__ dlo, long n4) {
  long i = (long)blockIdx.x * blockDim.x + threadIdx.x;
  long stride = (long)gridDim.x * blockDim.x;
  for (; i < n4; i += stride) {
    float4 v = src[i];
    short4 h, l;
    h.x = f2bf(v.x); l.x = f2bf(v.x - bf2f(h.x));
    h.y = f2bf(v.y); l.y = f2bf(v.y - bf2f(h.y));
    h.z = f2bf(v.z); l.z = f2bf(v.z - bf2f(h.z));
    h.w = f2bf(v.w); l.w = f2bf(v.w - bf2f(h.w));
    dhi[i] = h; dlo[i] = l;
  }
}

__launch_bounds__(256)
__global__ void transpose_cast_hl(const float* __restrict__ src, short* __restrict__ dhi,
                                  short* __restrict__ dlo, int K, int N) {
  __shared__ float tile[64][65];
  int k0 = blockIdx.x * 64, n0 = blockIdx.y * 64;
  for (int i = threadIdx.x; i < 4096; i += 256) {
    int r = i >> 6, c = i & 63;
    tile[r][c] = (n0 + c < N) ? src[(size_t)(k0 + r) * N + n0 + c] : 0.f;
  }
  __syncthreads();
  for (int i = threadIdx.x; i < 4096; i += 256) {
    int r = i >> 6, c = i & 63;
    float v = tile[c][r];
    short h = f2bf(v);
    dhi[(size_t)(n0 + r) * K + k0 + c] = h;
    dlo[(size_t)(n0 + r) * K + k0 + c] = f2bf(v - bf2f(h));
  }
}

// ---------------- LayerNorms ----------------

__launch_bounds__(256)
__global__ void ln_hl(const float* __restrict__ in, int ldi, int N,
                      const float* __restrict__ w, const float* __restrict__ b,
                      short* __restrict__ ohi, short* __restrict__ olo, int ldo) {
  const int row = blockIdx.x * 4 + (threadIdx.x >> 6);
  const int lane = threadIdx.x & 63;
  const float* r = in + (size_t)row * ldi;
  float s = 0.f, s2 = 0.f;
  for (int i = lane; i < N; i += 64) { float v = r[i]; s += v; s2 += v * v; }
#pragma unroll
  for (int off = 32; off >= 1; off >>= 1) { s += __shfl_xor(s, off); s2 += __shfl_xor(s2, off); }
  float mean = s / N, var = s2 / N - mean * mean;
  float rstd = rsqrtf(var + 1e-5f);
  for (int i = lane; i < N; i += 64) {
    float y = (r[i] - mean) * rstd * w[i];
    if (b) y += b[i];
    short h = f2bf(y);
    ohi[(size_t)row * ldo + i] = h;
    olo[(size_t)row * ldo + i] = f2bf(y - bf2f(h));
  }
}

__launch_bounds__(256)
__global__ void ln_qkv(const float* __restrict__ Ccat,
                       const float* __restrict__ qw, const float* __restrict__ qb,
                       const float* __restrict__ kw, const float* __restrict__ kb,
                       short* __restrict__ cqH, short* __restrict__ cqL,
                       short* __restrict__ kvH, short* __restrict__ kvL) {
  const int vrow = blockIdx.x * 4 + (threadIdx.x >> 6);
  const int lane = threadIdx.x & 63;
  const float* r; int N; const float* w; const float* b; short* oh; short* ol; int ldo; int row;
  if (vrow < 4096) {
    row = vrow; r = Ccat + (size_t)row * 928; N = 384; w = qw; b = qb; oh = cqH; ol = cqL; ldo = 384;
  } else {
    row = vrow - 4096; r = Ccat + (size_t)row * 928 + 384; N = 512; w = kw; b = kb; oh = kvH; ol = kvL; ldo = 512;
  }
  float s = 0.f, s2 = 0.f;
  for (int i = lane; i < N; i += 64) { float v = r[i]; s += v; s2 += v * v; }
#pragma unroll
  for (int off = 32; off >= 1; off >>= 1) { s += __shfl_xor(s, off); s2 += __shfl_xor(s2, off); }
  float mean = s / N, var = s2 / N - mean * mean;
  float rstd = rsqrtf(var + 1e-5f);
  for (int i = lane; i < N; i += 64) {
    float y = (r[i] - mean) * rstd * w[i] + b[i];
    short h = f2bf(y);
    oh[(size_t)row * ldo + i] = h;
    ol[(size_t)row * ldo + i] = f2bf(y - bf2f(h));
  }
}

__launch_bounds__(256)
__global__ void ln_bf_f32(const float* __restrict__ in, const float* __restrict__ w,
                          short* __restrict__ obf, float* __restrict__ of,
                          float* __restrict__ outInit) {
  const int row = blockIdx.x * 4 + (threadIdx.x >> 6);
  const int lane = threadIdx.x & 63;
  const float* r = in + (size_t)row * 768;
  float s = 0.f, s2 = 0.f;
  for (int i = lane; i < 768; i += 64) { float v = r[i]; s += v; s2 += v * v; }
#pragma unroll
  for (int off = 32; off >= 1; off >>= 1) { s += __shfl_xor(s, off); s2 += __shfl_xor(s2, off); }
  float mean = s / 768.f, var = s2 / 768.f - mean * mean;
  float rstd = rsqrtf(var + 1e-5f);
  for (int i = lane; i < 768; i += 64) {
    float xv = r[i];
    float y = (xv - mean) * rstd * w[i];
    obf[(size_t)row * 768 + i] = f2bf(y);
    of[(size_t)row * 768 + i] = y;
    outInit[(size_t)row * 768 + i] = xv;
  }
}

// ---------------- split-precision GEMM (chunk-swizzled LDS, BK=32) ----------------

template<int RESID>
__launch_bounds__(256)
__global__ void gemm3(const short* __restrict__ Ahi, const short* __restrict__ Alo, int lda,
                      const short* __restrict__ Bhi, const short* __restrict__ Blo, int ldb,
                      float* __restrict__ Cf, int ldc, const float* __restrict__ resid,
                      int M, int N, int K) {
  __shared__ __align__(16) short AsH[4096], AsL[4096], BsH[4096], BsL[4096];
  const int tid = threadIdx.x;
  int n0, m0; xcd_swz(n0, m0);
  const int wave = tid >> 6, lane = tid & 63;
  const int wm = (wave >> 1) * 64, wn = (wave & 1) * 64;
  const int lr = lane & 15, rb = (lane >> 4) * 4;
  const int stg = ((tid & 3) ^ ((tid >> 3) & 3)) * 8;
  const int lkx = (((lane >> 4) ^ ((lr >> 1) & 3))) * 8;
  const floatx4 fz = {0.f, 0.f, 0.f, 0.f};
  floatx4 acc[4][4];
#pragma unroll
  for (int i = 0; i < 4; i++)
#pragma unroll
    for (int j = 0; j < 4; j++) acc[i][j] = fz;
  const size_t rowA = (size_t)(m0 + (tid >> 2)) * lda + stg;
  const size_t rowB = (size_t)(n0 + (tid >> 2)) * ldb + stg;
  const size_t a64 = (size_t)64 * lda, b64 = (size_t)64 * ldb;
  short* AsHW = AsH + wave * 512; short* AsLW = AsL + wave * 512;
  short* BsHW = BsH + wave * 512; short* BsLW = BsL + wave * 512;
  for (int k0 = 0; k0 < K; k0 += 32) {
    async16(AsHW, Ahi + rowA + k0);        async16(AsHW + 2048, Ahi + rowA + a64 + k0);
    async16(AsLW, Alo + rowA + k0);        async16(AsLW + 2048, Alo + rowA + a64 + k0);
    async16(BsHW, Bhi + rowB + k0);        async16(BsHW + 2048, Bhi + rowB + b64 + k0);
    async16(BsLW, Blo + rowB + k0);        async16(BsLW + 2048, Blo + rowB + b64 + k0);
    __syncthreads();
    short8 ah[4], al[4], bh[4], bl[4];
#pragma unroll
    for (int i = 0; i < 4; i++) {
      ah[i] = *(const short8*)&AsH[(wm + i * 16 + lr) * 32 + lkx];
      al[i] = *(const short8*)&AsL[(wm + i * 16 + lr) * 32 + lkx];
    }
#pragma unroll
    for (int j = 0; j < 4; j++) {
      bh[j] = *(const short8*)&BsH[(wn + j * 16 + lr) * 32 + lkx];
      bl[j] = *(const short8*)&BsL[(wn + j * 16 + lr) * 32 + lkx];
    }
#pragma unroll
    for (int i = 0; i < 4; i++)
#pragma unroll
      for (int j = 0; j < 4; j++) {
        acc[i][j] = mfma16(ah[i], bh[j], acc[i][j]);
        acc[i][j] = mfma16(ah[i], bl[j], acc[i][j]);
        acc[i][j] = mfma16(al[i], bh[j], acc[i][j]);
      }
    __syncthreads();
  }
#pragma unroll
  for (int i = 0; i < 4; i++) {
    int row = m0 + wm + i * 16 + rb;
#pragma unroll
    for (int j = 0; j < 4; j++) {
      int col = n0 + wn + j * 16 + lr;
      if (col < N) {
#pragma unroll
        for (int r = 0; r < 4; r++) {
          int rr = row + r;
          if (rr < M) {
            float v = acc[i][j][r];
            if (RESID) v += resid[(size_t)rr * ldc + col];
            Cf[(size_t)rr * ldc + col] = v;
          }
        }
      }
    }
  }
}

// ---------------- plain bf16 GEMM + gelu -> bf16 out (shared fc), BK=64 ----------------

__launch_bounds__(256)
__global__ void gemm_fc(const short* __restrict__ A, int lda,
                        const short* __restrict__ Bt, int ldb,
                        short* __restrict__ Cb, int ldc, int K) {
  __shared__ __align__(16) short As[8192], Bs[8192];
  const int tid = threadIdx.x;
  int n0, m0; xcd_swz(n0, m0);
  const int wave = tid >> 6, lane = tid & 63;
  const int wm = (wave >> 1) * 64, wn = (wave & 1) * 64;
  const int lr = lane & 15, q4 = lane >> 4, rb = q4 * 4;
  const int srow = tid >> 3;
  const int sg = ((tid & 7) ^ (srow & 7)) * 8;
  const int cx0 = ((q4 ^ (lr & 7))) * 8;
  const int cx1 = (((4 + q4) ^ (lr & 7))) * 8;
  const floatx4 fz = {0.f, 0.f, 0.f, 0.f};
  floatx4 acc[4][4];
#pragma unroll
  for (int i = 0; i < 4; i++)
#pragma unroll
    for (int j = 0; j < 4; j++) acc[i][j] = fz;
  const short* Ag = A + (size_t)(m0 + srow) * lda + sg;
  const short* Bg = Bt + (size_t)(n0 + srow) * ldb + sg;
  short* AsW = As + wave * 512; short* BsW = Bs + wave * 512;
  const size_t a32 = (size_t)32 * lda, b32 = (size_t)32 * ldb;
  for (int k0 = 0; k0 < K; k0 += 64) {
    async16(AsW,        Ag + k0);            async16(AsW + 2048, Ag + a32 + k0);
    async16(AsW + 4096, Ag + 2 * a32 + k0);  async16(AsW + 6144, Ag + 3 * a32 + k0);
    async16(BsW,        Bg + k0);            async16(BsW + 2048, Bg + b32 + k0);
    async16(BsW + 4096, Bg + 2 * b32 + k0);  async16(BsW + 6144, Bg + 3 * b32 + k0);
    __syncthreads();
#pragma unroll
    for (int ks = 0; ks < 2; ks++) {
      const int cx = ks ? cx1 : cx0;
      short8 af[4], bfr[4];
#pragma unroll
      for (int i = 0; i < 4; i++) af[i] = *(const short8*)&As[(wm + i * 16 + lr) * 64 + cx];
#pragma unroll
      for (int j = 0; j < 4; j++) bfr[j] = *(const short8*)&Bs[(wn + j * 16 + lr) * 64 + cx];
#pragma unroll
      for (int i = 0; i < 4; i++)
#pragma unroll
        for (int j = 0; j < 4; j++) acc[i][j] = mfma16(af[i], bfr[j], acc[i][j]);
    }
    __syncthreads();
  }
#pragma unroll
  for (int i = 0; i < 4; i++) {
    int row = m0 + wm + i * 16 + rb;
#pragma unroll
    for (int j = 0; j < 4; j++) {
      int col = n0 + wn + j * 16 + lr;
#pragma unroll
      for (int r = 0; r < 4; r++)
        Cb[(size_t)(row + r) * ldc + col] = f2bf(gelu_f(acc[i][j][r]));
    }
  }
}

// ---------------- shared proj: 128x64 tile, split-k3, NO atomics ----------------

__launch_bounds__(256)
__global__ void gemm_sk(const short* __restrict__ A, int lda,
                        const short* __restrict__ Bt, int ldb,
                        float* __restrict__ out, int ldc,
                        float* __restrict__ p1, float* __restrict__ p2, int klen) {
  __shared__ __align__(16) short As[8192], Bs[4096];
  const int tid = threadIdx.x;
  const int m0 = blockIdx.y * 128, n0 = blockIdx.x * 64;
  const int z = blockIdx.z;
  const int koff = z * klen;
  const int wave = tid >> 6, lane = tid & 63;
  const int wm = (wave >> 1) * 64, wn = (wave & 1) * 32;
  const int lr = lane & 15, q4 = lane >> 4, rb = q4 * 4;
  const int srow = tid >> 3;
  const int sg = ((tid & 7) ^ (srow & 7)) * 8;
  const int cx0 = ((q4 ^ (lr & 7))) * 8;
  const int cx1 = (((4 + q4) ^ (lr & 7))) * 8;
  const floatx4 fz = {0.f, 0.f, 0.f, 0.f};
  floatx4 acc[4][2];
#pragma unroll
  for (int i = 0; i < 4; i++)
#pragma unroll
    for (int j = 0; j < 2; j++) acc[i][j] = fz;
  const short* Ag = A + (size_t)(m0 + srow) * lda + koff + sg;
  const short* Bg = Bt + (size_t)(n0 + srow) * ldb + koff + sg;
  short* AsW = As + wave * 512; short* BsW = Bs + wave * 512;
  const size_t a32 = (size_t)32 * lda, b32 = (size_t)32 * ldb;
  for (int k0 = 0; k0 < klen; k0 += 64) {
    async16(AsW,        Ag + k0);            async16(AsW + 2048, Ag + a32 + k0);
    async16(AsW + 4096, Ag + 2 * a32 + k0);  async16(AsW + 6144, Ag + 3 * a32 + k0);
    async16(BsW,        Bg + k0);            async16(BsW + 2048, Bg + b32 + k0);
    __syncthreads();
#pragma unroll
    for (int ks = 0; ks < 2; ks++) {
      const int cx = ks ? cx1 : cx0;
      short8 af[4], bfr[2];
#pragma unroll
      for (int i = 0; i < 4; i++) af[i] = *(const short8*)&As[(wm + i * 16 + lr) * 64 + cx];
#pragma unroll
      for (int j = 0; j < 2; j++) bfr[j] = *(const short8*)&Bs[(wn + j * 16 + lr) * 64 + cx];
#pragma unroll
      for (int i = 0; i < 4; i++)
#pragma unroll
        for (int j = 0; j < 2; j++) acc[i][j] = mfma16(af[i], bfr[j], acc[i][j]);
    }
    __syncthreads();
  }
  float* dst = (z == 0) ? out : (z == 1 ? p1 : p2);
#pragma unroll
  for (int i = 0; i < 4; i++) {
    int row = m0 + wm + i * 16 + rb;
#pragma unroll
    for (int j = 0; j < 2; j++) {
      int col = n0 + wn + j * 16 + lr;
#pragma unroll
      for (int r = 0; r < 4; r++) {
        size_t idx = (size_t)(row + r) * ldc + col;
        if (z == 0) dst[idx] += acc[i][j][r];
        else dst[idx] = acc[i][j][r];
      }
    }
  }
}

__global__ void sk_reduce(float4* __restrict__ out, const float4* __restrict__ p1,
                          const float4* __restrict__ p2) {
  int i = blockIdx.x * 256 + threadIdx.x;
  const int stride = gridDim.x * 256;
  for (; i < 786432; i += stride) {
    float4 o = out[i], a = p1[i], b = p2[i];
    o.x += a.x + b.x;
    o.y += a.y + b.y;
    o.z += a.z + b.z;
    o.w += a.w + b.w;
    out[i] = o;
  }
}

// ---------------- RoPE builders (hi/lo) ----------------

__global__ void build_qk(const float* __restrict__ Qf, const float* __restrict__ KVf,
                         const float* __restrict__ Ccat,
                         short* __restrict__ qh, short* __restrict__ ql,
                         short* __restrict__ kh, short* __restrict__ kl) {
  int id = blockIdx.x * blockDim.x + threadIdx.x;
  if (id >= 4096 * 12) return;
  int token = id / 12, hh_ = id - token * 12;
  int s = token & 1023, b = token >> 10;
  size_t base = ((size_t)(b * 12 + hh_) * 1024 + s) * 64;
  float vals[64];
  if (blockIdx.y == 0) {
    const float* q = Qf + (size_t)token * 768 + hh_ * 64;
#pragma unroll
    for (int d = 0; d < 32; d++) vals[d] = q[d];
#pragma unroll
    for (int i = 0; i < 16; i++) {
      float fi = powf(10000.f, -(float)(2 * i) / 64.f);
      float sn, cs; sincosf((float)s * fi, &sn, &cs);
      vals[32 + i] = q[32 + i] * cs - q[48 + i] * sn;
      vals[48 + i] = q[48 + i] * cs + q[32 + i] * sn;
    }
#pragma unroll
    for (int d = 0; d < 64; d++) {
      short h = f2bf(vals[d]);
      qh[base + d] = h; ql[base + d] = f2bf(vals[d] - bf2f(h));
    }
  } else {
    const float* kv = KVf + (size_t)token * 1152 + hh_ * 96;
#pragma unroll
    for (int d = 0; d < 32; d++) vals[d] = kv[d];
    const float* kr = Ccat + (size_t)token * 928 + 896;
#pragma unroll
    for (int i = 0; i < 16; i++) {
      float fi = powf(10000.f, -(float)(2 * i) / 64.f);
      float sn, cs; sincosf((float)s * fi, &sn, &cs);
      vals[32 + i] = kr[i] * cs - kr[16 + i] * sn;
      vals[48 + i] = kr[16 + i] * cs + kr[i] * sn;
    }
#pragma unroll
    for (int d = 0; d < 64; d++) {
      short h = f2bf(vals[d]);
      kh[base + d] = h; kl[base + d] = f2bf(vals[d] - bf2f(h));
    }
  }
}

__launch_bounds__(256)
__global__ void build_vt_hl(const float* __restrict__ KVf,
                            short* __restrict__ vth, short* __restrict__ vtl) {
  __shared__ float tile[64][65];
  const int s0 = blockIdx.x * 64, bh = blockIdx.y;
  const int b = bh / 12, h = bh - b * 12;
  for (int i = threadIdx.x; i < 4096; i += 256) {
    int tl = i >> 6, d = i & 63;
    int token = b * 1024 + s0 + tl;
    tile[tl][d] = KVf[(size_t)token * 1152 + h * 96 + 32 + d];
  }
  __syncthreads();
  for (int i = threadIdx.x; i < 4096; i += 256) {
    int d = i >> 6, sl = i & 63;
    float v = tile[sl][d];
    short hh = f2bf(v);
    size_t idx = (size_t)bh * 65536 + (size_t)d * 1024 + s0 + sl;
    vth[idx] = hh;
    vtl[idx] = f2bf(v - bf2f(hh));
  }
}

// ---------------- flash attention (swizzled, padded P, paired q-tiles) ----------------

__launch_bounds__(256)
__global__ void attn3(const short* __restrict__ qbh, const short* __restrict__ qbl,
                      const short* __restrict__ kbh, const short* __restrict__ kbl,
                      const short* __restrict__ vth, const short* __restrict__ vtl,
                      short* __restrict__ obh, short* __restrict__ obl) {
  const int bh = blockIdx.y;
  const int b = bh / 12, h = bh - b * 12;
  const short* Qh = qbh + (size_t)bh * 65536;
  const short* Ql = qbl + (size_t)bh * 65536;
  const short* Kh = kbh + (size_t)bh * 65536;
  const short* Kl = kbl + (size_t)bh * 65536;
  const short* Vh = vth + (size_t)bh * 65536;
  const short* Vl = vtl + (size_t)bh * 65536;
  __shared__ __align__(16) short KsH[4096], KsL[4096], VsH[4096], VsL[4096];
  __shared__ __align__(16) short PsH[4608], PsL[4608];
  const int tid = threadIdx.x, wave = tid >> 6, lane = tid & 63;
  const int lr = lane & 15, q4 = lane >> 4, lk = (lane >> 4) * 8;
  const int sx0 = ((q4 ^ (lr & 7))) * 8;
  const int sx1 = (((4 + q4) ^ (lr & 7))) * 8;
  const int soff_sw = (((tid & 7) ^ ((tid >> 3) & 7))) * 8;
  const int srow = tid >> 3;
  short* KsHW = KsH + wave * 512; short* KsLW = KsL + wave * 512;
  short* VsHW = VsH + wave * 512; short* VsLW = VsL + wave * 512;
  short* myPh = PsH + wave * 1152; short* myPl = PsL + wave * 1152;
  const floatx4 fz = {0.f, 0.f, 0.f, 0.f};
#pragma unroll
  for (int ph = 0; ph < 2; ph++) {
    const int qt = ph ? 15 - blockIdx.x : blockIdx.x;
    const int qrow0 = qt * 64 + wave * 16;
    short8 qfh[2], qfl[2];
    qfh[0] = *(const short8*)&Qh[(size_t)(qrow0 + lr) * 64 + lk];
    qfh[1] = *(const short8*)&Qh[(size_t)(qrow0 + lr) * 64 + 32 + lk];
    qfl[0] = *(const short8*)&Ql[(size_t)(qrow0 + lr) * 64 + lk];
    qfl[1] = *(const short8*)&Ql[(size_t)(qrow0 + lr) * 64 + 32 + lk];
    floatx4 oacc[4];
#pragma unroll
    for (int t = 0; t < 4; t++) oacc[t] = fz;
    float m_i[4], l_i[4];
#pragma unroll
    for (int r = 0; r < 4; r++) { m_i[r] = -__builtin_inff(); l_i[r] = 0.f; }
    for (int kt = 0; kt <= qt; kt++) {
      __syncthreads();
      size_t krow = (size_t)(kt * 64 + srow) * 64 + soff_sw;
      size_t vrow = (size_t)srow * 1024 + kt * 64 + soff_sw;
      async16(KsHW, Kh + krow);        async16(KsHW + 2048, Kh + krow + 32 * 64);
      async16(KsLW, Kl + krow);        async16(KsLW + 2048, Kl + krow + 32 * 64);
      async16(VsHW, Vh + vrow);        async16(VsHW + 2048, Vh + vrow + 32 * 1024);
      async16(VsLW, Vl + vrow);        async16(VsLW + 2048, Vl + vrow + 32 * 1024);
      __syncthreads();
      floatx4 sacc[4];
#pragma unroll
      for (int j = 0; j < 4; j++) sacc[j] = fz;
#pragma unroll
      for (int j = 0; j < 4; j++) {
        int rbase = (j * 16 + lr) * 64;
        short8 kh0 = *(const short8*)&KsH[rbase + sx0];
        short8 kh1 = *(const short8*)&KsH[rbase + sx1];
        short8 kl0 = *(const short8*)&KsL[rbase + sx0];
        short8 kl1 = *(const short8*)&KsL[rbase + sx1];
        sacc[j] = mfma16(qfh[0], kh0, sacc[j]);
        sacc[j] = mfma16(qfh[1], kh1, sacc[j]);
        sacc[j] = mfma16(qfh[0], kl0, sacc[j]);
        sacc[j] = mfma16(qfh[1], kl1, sacc[j]);
        sacc[j] = mfma16(qfl[0], kh0, sacc[j]);
        sacc[j] = mfma16(qfl[1], kh1, sacc[j]);
      }
      float pv[4][4], mrow[4];
#pragma unroll
      for (int r = 0; r < 4; r++) mrow[r] = -__builtin_inff();
      const bool diag = (kt == qt);
#pragma unroll
      for (int j = 0; j < 4; j++)
#pragma unroll
        for (int r = 0; r < 4; r++) {
          float v = sacc[j][r] * 0.125f;
          if (diag) {
            int qg = qrow0 + q4 * 4 + r;
            int kg = kt * 64 + j * 16 + lr;
            if (kg > qg) v = -__builtin_inff();
          }
          pv[j][r] = v;
          mrow[r] = fmaxf(mrow[r], v);
        }
#pragma unroll
      for (int r = 0; r < 4; r++)
#pragma unroll
        for (int off = 1; off < 16; off <<= 1) mrow[r] = fmaxf(mrow[r], __shfl_xor(mrow[r], off));
      float alpha[4], rsum[4];
#pragma unroll
      for (int r = 0; r < 4; r++) {
        float nm = fmaxf(m_i[r], mrow[r]);
        alpha[r] = __expf(m_i[r] - nm);
        m_i[r] = nm; rsum[r] = 0.f;
      }
#pragma unroll
      for (int j = 0; j < 4; j++)
#pragma unroll
        for (int r = 0; r < 4; r++) {
          float pe = __expf(pv[j][r] - m_i[r]);
          pv[j][r] = pe; rsum[r] += pe;
        }
#pragma unroll
      for (int r = 0; r < 4; r++) {
#pragma unroll
        for (int off = 1; off < 16; off <<= 1) rsum[r] += __shfl_xor(rsum[r], off);
        l_i[r] = l_i[r] * alpha[r] + rsum[r];
      }
#pragma unroll
      for (int t = 0; t < 4; t++)
#pragma unroll
        for (int r = 0; r < 4; r++) oacc[t][r] *= alpha[r];
#pragma unroll
      for (int j = 0; j < 4; j++)
#pragma unroll
        for (int r = 0; r < 4; r++) {
          float p = pv[j][r];
          short hh = f2bf(p);
          myPh[(q4 * 4 + r) * 72 + j * 16 + lr] = hh;
          myPl[(q4 * 4 + r) * 72 + j * 16 + lr] = f2bf(p - bf2f(hh));
        }
      __asm__ volatile("s_waitcnt lgkmcnt(0)" ::: "memory");
#pragma unroll
      for (int c = 0; c < 2; c++) {
        short8 ph_ = *(const short8*)&myPh[lr * 72 + c * 32 + lk];
        short8 pl_ = *(const short8*)&myPl[lr * 72 + c * 32 + lk];
        const int sxc = c ? sx1 : sx0;
#pragma unroll
        for (int t = 0; t < 4; t++) {
          int rbase = (t * 16 + lr) * 64;
          short8 vh = *(const short8*)&VsH[rbase + sxc];
          short8 vl = *(const short8*)&VsL[rbase + sxc];
          oacc[t] = mfma16(ph_, vh, oacc[t]);
          oacc[t] = mfma16(ph_, vl, oacc[t]);
          oacc[t] = mfma16(pl_, vh, oacc[t]);
        }
      }
    }
#pragma unroll
    for (int t = 0; t < 4; t++)
#pragma unroll
      for (int r = 0; r < 4; r++) {
        int s = qrow0 + q4 * 4 + r;
        int token = b * 1024 + s;
        float ov = oacc[t][r] / l_i[r];
        short hh = f2bf(ov);
        size_t idx = (size_t)token * 768 + h * 64 + t * 16 + lr;
        obh[idx] = hh;
        obl[idx] = f2bf(ov - bf2f(hh));
      }
  }
}

// ---------------- routing ----------------

__launch_bounds__(256)
__global__ void route_score(const float* __restrict__ h2f, const float* __restrict__ cent,
                            const float* __restrict__ rbias,
                            int* __restrict__ topexp, float* __restrict__ gates) {
  const int token = blockIdx.x * 4 + (threadIdx.x >> 6);
  const int lane = threadIdx.x & 63;
  const float* hv = h2f + (size_t)token * 768;
  float hreg[12];
#pragma unroll
  for (int ii = 0; ii < 12; ii++) hreg[ii] = hv[lane + 64 * ii];
  float raw[8];
#pragma unroll
  for (int e = 0; e < 8; e++) {
    const float* cv = cent + e * 768;
    float p = 0.f;
#pragma unroll
    for (int ii = 0; ii < 12; ii++) p += hreg[ii] * cv[lane + 64 * ii];
#pragma unroll
    for (int off = 32; off >= 1; off >>= 1) p += __shfl_xor(p, off);
    raw[e] = p;
  }
  if (lane == 0) {
    float b0 = -__builtin_inff(); int i1 = 0;
#pragma unroll
    for (int e = 0; e < 8; e++) { float be = raw[e] + rbias[e]; if (be > b0) { b0 = be; i1 = e; } }
    float b1 = -__builtin_inff(); int i2 = 0;
#pragma unroll
    for (int e = 0; e < 8; e++) {
      if (e == i1) continue;
      float be = raw[e] + rbias[e];
      if (be > b1) { b1 = be; i2 = e; }
    }
    float w1 = 1.f / (1.f + expf(-raw[i1]));
    float w2 = 1.f / (1.f + expf(-raw[i2]));
    float wsum = w1 + w2 + 1e-9f;
    topexp[token] = i1;        gates[token] = w1 / wsum;
    topexp[4096 + token] = i2; gates[4096 + token] = w2 / wsum;
  }
}

__launch_bounds__(256)
__global__ void build_lists(const int* __restrict__ topexp,
                            int* __restrict__ counts, int* __restrict__ lists) {
  const int e = blockIdx.x;
  __shared__ int wave_off[4];
  const int wave = threadIdx.x >> 6, lane = threadIdx.x & 63;
  int total = 0;
  for (int c0 = 0; c0 < 8192; c0 += 256) {
    int slot = c0 + threadIdx.x;
    bool m = (topexp[slot] == e);
    unsigned long long bal = __ballot(m);
    int wcnt = __popcll(bal);
    int lpre = __popcll(bal & ((1ull << lane) - 1ull));
    if (lane == 0) wave_off[wave] = wcnt;
    __syncthreads();
    int woff = 0;
#pragma unroll
    for (int w = 0; w < 4; w++) if (w < wave) woff += wave_off[w];
    int chunk_total = wave_off[0] + wave_off[1] + wave_off[2] + wave_off[3];
    if (m) lists[e * 4096 + total + woff + lpre] = slot;
    total += chunk_total;
    __syncthreads();
  }
  if (threadIdx.x == 0) counts[e] = total;
}

// ---------------- routed-expert GEMMs: 8 experts, e = XCD ----------------

__launch_bounds__(256)
__global__ void expert_fc_z(const short* __restrict__ h2bf, const short* __restrict__ wfc,
                            const int* __restrict__ lists, const int* __restrict__ counts,
                            short* __restrict__ act) {
  int e, m0, n0; eswz(128, e, m0, n0);
  const int cnt = counts[e];
  if (m0 >= cnt) return;
  int aoff = 0;
  for (int i = 0; i < e; i++) aoff += counts[i];
  __shared__ __align__(16) short As[8192], Bs[8192];
  __shared__ int slots[128];
  const int tid = threadIdx.x;
  if (tid < 128) slots[tid] = lists[e * 4096 + m0 + tid];
  __syncthreads();
  const int wave = tid >> 6, lane = tid & 63;
  const int wm = (wave >> 1) * 64, wn = (wave & 1) * 64;
  const int lr = lane & 15, q4 = lane >> 4, rb = q4 * 4;
  const int srow = tid >> 3;
  const int sg = ((tid & 7) ^ (srow & 7)) * 8;
  const int cx0 = ((q4 ^ (lr & 7))) * 8;
  const int cx1 = (((4 + q4) ^ (lr & 7))) * 8;
  int tok[4];
#pragma unroll
  for (int p = 0; p < 4; p++) tok[p] = slots[p * 32 + srow] & 4095;
  const floatx4 fz = {0.f, 0.f, 0.f, 0.f};
  floatx4 acc[4][4];
#pragma unroll
  for (int i = 0; i < 4; i++)
#pragma unroll
    for (int j = 0; j < 4; j++) acc[i][j] = fz;
  const short* Ag0 = h2bf + (size_t)tok[0] * 768 + sg;
  const short* Ag1 = h2bf + (size_t)tok[1] * 768 + sg;
  const short* Ag2 = h2bf + (size_t)tok[2] * 768 + sg;
  const short* Ag3 = h2bf + (size_t)tok[3] * 768 + sg;
  const short* Bg = wfc + (size_t)e * (3072 * 768) + (size_t)(n0 + srow) * 768 + sg;
  short* AsW = As + wave * 512; short* BsW = Bs + wave * 512;
  const size_t b32 = (size_t)32 * 768;
  for (int k0 = 0; k0 < 768; k0 += 64) {
    async16(AsW,        Ag0 + k0);           async16(AsW + 2048, Ag1 + k0);
    async16(AsW + 4096, Ag2 + k0);           async16(AsW + 6144, Ag3 + k0);
    async16(BsW,        Bg + k0);            async16(BsW + 2048, Bg + b32 + k0);
    async16(BsW + 4096, Bg + 2 * b32 + k0);  async16(BsW + 6144, Bg + 3 * b32 + k0);
    __syncthreads();
#pragma unroll
    for (int ks = 0; ks < 2; ks++) {
      const int cx = ks ? cx1 : cx0;
      short8 af[4], bfr[4];
#pragma unroll
      for (int i = 0; i < 4; i++) af[i] = *(const short8*)&As[(wm + i * 16 + lr) * 64 + cx];
#pragma unroll
      for (int j = 0; j < 4; j++) bfr[j] = *(const short8*)&Bs[(wn + j * 16 + lr) * 64 + cx];
#pragma unroll
      for (int i = 0; i < 4; i++)
#pragma unroll
        for (int j = 0; j < 4; j++) acc[i][j] = mfma16(af[i], bfr[j], acc[i][j]);
    }
    __syncthreads();
  }
#pragma unroll
  for (int i = 0; i < 4; i++) {
    int lrow = wm + i * 16 + rb;
#pragma unroll
    for (int j = 0; j < 4; j++) {
      int col = n0 + wn + j * 16 + lr;
#pragma unroll
      for (int r = 0; r < 4; r++) {
        if (m0 + lrow + r < cnt)
          act[(size_t)(aoff + m0 + lrow + r) * 3072 + col] = f2bf(gelu_f(acc[i][j][r]));
      }
    }
  }
}

// proj: full K=3072 per block (48 iters), plain bf16 stores into slot-indexed routed plane.
__launch_bounds__(256)
__global__ void expert_proj_one(const short* __restrict__ act, const short* __restrict__ wproj,
                                const int* __restrict__ lists, const int* __restrict__ counts,
                                short* __restrict__ routed) {
  int e, m0, n0; eswz(64, e, m0, n0);
  const int cnt = counts[e];
  if (m0 >= cnt) return;
  int aoff = 0;
  for (int i = 0; i < e; i++) aoff += counts[i];
  __shared__ __align__(16) short As[8192], Bs[4096];
  __shared__ int slots[128];
  const int tid = threadIdx.x;
  if (tid < 128) slots[tid] = lists[e * 4096 + m0 + tid];
  __syncthreads();
  const int wave = tid >> 6, lane = tid & 63;
  const int wm = (wave >> 1) * 64, wn = (wave & 1) * 32;
  const int lr = lane & 15, q4 = lane >> 4, rb = q4 * 4;
  const int srow = tid >> 3;
  const int sg = ((tid & 7) ^ (srow & 7)) * 8;
  const int cx0 = ((q4 ^ (lr & 7))) * 8;
  const int cx1 = (((4 + q4) ^ (lr & 7))) * 8;
  const floatx4 fz = {0.f, 0.f, 0.f, 0.f};
  floatx4 acc[4][2];
#pragma unroll
  for (int i = 0; i < 4; i++)
#pragma unroll
    for (int j = 0; j < 2; j++) acc[i][j] = fz;
  const short* Ag = act + (size_t)(aoff + m0 + srow) * 3072 + sg;
  const short* Bg = wproj + (size_t)e * (768 * 3072) + (size_t)(n0 + srow) * 3072 + sg;
  short* AsW = As + wave * 512; short* BsW = Bs + wave * 512;
  const size_t s32 = (size_t)32 * 3072;
  for (int k0 = 0; k0 < 3072; k0 += 64) {
    async16(AsW,        Ag + k0);            async16(AsW + 2048, Ag + s32 + k0);
    async16(AsW + 4096, Ag + 2 * s32 + k0);  async16(AsW + 6144, Ag + 3 * s32 + k0);
    async16(BsW,        Bg + k0);            async16(BsW + 2048, Bg + s32 + k0);
    __syncthreads();
#pragma unroll
    for (int ks = 0; ks < 2; ks++) {
      const int cx = ks ? cx1 : cx0;
      short8 af[4], bfr[2];
#pragma unroll
      for (int i = 0; i < 4; i++) af[i] = *(const short8*)&As[(wm + i * 16 + lr) * 64 + cx];
#pragma unroll
      for (int j = 0; j < 2; j++) bfr[j] = *(const short8*)&Bs[(wn + j * 16 + lr) * 64 + cx];
#pragma unroll
      for (int i = 0; i < 4; i++)
#pragma unroll
        for (int j = 0; j < 2; j++) acc[i][j] = mfma16(af[i], bfr[j], acc[i][j]);
    }
    __syncthreads();
  }
#pragma unroll
  for (int i = 0; i < 4; i++) {
    int lrow = wm + i * 16 + rb;
#pragma unroll
    for (int j = 0; j < 2; j++) {
      int col = n0 + wn + j * 16 + lr;
#pragma unroll
      for (int r = 0; r < 4; r++) {
        if (m0 + lrow + r < cnt)
          routed[(size_t)slots[lrow + r] * 768 + col] = f2bf(acc[i][j][r]);
      }
    }
  }
}

// out[t] += g1*routed[t] + g2*routed[4096+t]  (slots are t and 4096+t by construction)
__global__ void gather_routed(const short* __restrict__ routed, const float* __restrict__ gates,
                              float* __restrict__ out) {
  int i = blockIdx.x * 256 + threadIdx.x;     // 393216 = 4096 * 96
  if (i >= 393216) return;
  int t = i / 96, c = (i - t * 96) * 8;
  float g1 = gates[t], g2 = gates[4096 + t];
  short8 a = *(const short8*)&routed[(size_t)t * 768 + c];
  short8 b = *(const short8*)&routed[(size_t)(4096 + t) * 768 + c];
  float* o = &out[(size_t)t * 768 + c];
  float4 o0 = *(float4*)o, o1 = *(float4*)(o + 4);
  o0.x += g1 * bf2f(a[0]) + g2 * bf2f(b[0]);
  o0.y += g1 * bf2f(a[1]) + g2 * bf2f(b[1]);
  o0.z += g1 * bf2f(a[2]) + g2 * bf2f(b[2]);
  o0.w += g1 * bf2f(a[3]) + g2 * bf2f(b[3]);
  o1.x += g1 * bf2f(a[4]) + g2 * bf2f(b[4]);
  o1.y += g1 * bf2f(a[5]) + g2 * bf2f(b[5]);
  o1.z += g1 * bf2f(a[6]) + g2 * bf2f(b[6]);
  o1.w += g1 * bf2f(a[7]) + g2 * bf2f(b[7]);
  *(float4*)o = o0;
  *(float4*)(o + 4) = o1;
}

__global__ void bad_kernel(float* out) { out[threadIdx.x] = 1e30f; }

// ---------------- launch ----------------

extern "C" void kernel_launch(void* const* d_in, const int* in_sizes, int n_in,
                              void* d_out, int out_size, void* d_ws, size_t ws_size,
                              hipStream_t stream) {
  const float* x = (const float*)d_in[0];
  const float* ln1_w = (const float*)d_in[1];
  const float* ln2_w = (const float*)d_in[2];
  const float* W_dq = (const float*)d_in[3];
  const float* W_uq = (const float*)d_in[4];
  const float* q_ln_w = (const float*)d_in[5];
  const float* q_ln_b = (const float*)d_in[6];
  const float* W_dkv = (const float*)d_in[7];
  const float* W_ukv = (const float*)d_in[8];
  const float* kv_ln_w = (const float*)d_in[9];
  const float* kv_ln_b = (const float*)d_in[10];
  const float* W_o = (const float*)d_in[11];
  const float* s_fc = (const float*)d_in[12];
  const float* s_proj = (const float*)d_in[13];
  const float* e_fc = (const float*)d_in[14];
  const float* e_proj = (const float*)d_in[15];
  const float* cent = (const float*)d_in[16];
  const float* rbias = (const float*)d_in[17];
  float* out = (float*)d_out;

  char* base = (char*)d_ws;
  size_t off = 0;
  auto take = [&](size_t bytes) -> char* {
    char* r = base + off;
    off = (off + bytes + 255) & ~(size_t)255;
    return r;
  };
  short* WcatH = (short*)take(1572864);  short* WcatL = (short*)take(1572864);
  short* WuqH  = (short*)take(589824);   short* WuqL  = (short*)take(589824);
  short* WukvH = (short*)take(1179648);  short* WukvL = (short*)take(1179648);
  short* WoH   = (short*)take(1179648);  short* WoL   = (short*)take(1179648);
  float* x2    = (float*)take(12582912);
  float* gates = (float*)take(32768);
  int*   counts= (int*)take(32);
  int*   lists = (int*)take(131072);
  int*   topexp= (int*)take(32768);
  const size_t PLANE = 6291456;
  char* pool = take(4 * 2 * PLANE);        // 50.33 MB, pA..pD contiguous
  char* R    = take(51118080);             // 50.33 MB + 128-row pad
  size_t used = off;
  if (used > ws_size) { bad_kernel<<<1, 256, 0, stream>>>(out); return; }
  char* pA = pool;
  char* pB = pool + 2 * PLANE;
  char* pC = pool + 4 * PLANE;
  char* pD = pool + 6 * PLANE;

  // phase A overlays
  short* hH   = (short*)pA;            short* hL   = (short*)(pA + PLANE);
  float* Ccat = (float*)R;                                   // 4096x928 f32 (15.2 MB)
  short* cqH  = (short*)pB;            short* cqL  = (short*)(pB + 3145728);
  short* kvlH = (short*)pD;            short* kvlL = (short*)(pD + 4194304);
  float* Qf   = (float*)pC;
  float* KVf  = (float*)(R + 15204352);                      // 4096x1152 f32 (18.9 MB)
  short* qbH  = (short*)pD;            short* qbL  = (short*)(pD + PLANE);
  short* kbH  = (short*)pA;            short* kbL  = (short*)(pA + PLANE);
  short* vtH  = (short*)pB;            short* vtL  = (short*)(pB + PLANE);
  short* obH  = (short*)pC;            short* obL  = (short*)(pC + PLANE);
  // phase B overlays
  short* h2bf    = (short*)(pD + PLANE);                     // [44.04, 50.33) — live all phase B
  float* h2f     = (float*)pC;
  short* sfcCat  = (short*)pA;                               // 6144x768 bf16 (9.4 MB)
  short* sprojCat= (short*)(pA + 9437184);                   // 768x6144 bf16
  short* actCat  = (short*)R;                                // 4096x6144 bf16 (50.3 MB)
  short* ewAll   = (short*)pA;                               // 8x(3072x768) bf16 = 37.75 MB [0,37.75)
  short* eact    = (short*)R;                                // 8192 rows x 3072 bf16 = 50.33 MB
  short* routed  = (short*)x2;                               // 8192x768 bf16 = 12.58 MB (exact)
  // gemm_sk partial planes — dead at gemm_sk time; consumed by sk_reduce before expert casts
  float* skP1 = (float*)pC;            // h2f dead after route_score
  float* skP2 = x2;                    // x2 dead after ln_bf_f32

  // ---- weight prep ----
  cast_hl4<<<576, 256, 0, stream>>>((const float4*)W_o, (short4*)WoH, (short4*)WoL, 147456);
  transpose_cast_hl<<<dim3(12, 6), 256, 0, stream>>>(W_dq, WcatH, WcatL, 768, 384);
  transpose_cast_hl<<<dim3(12, 10), 256, 0, stream>>>(W_dkv, WcatH + (size_t)384 * 768,
                                                      WcatL + (size_t)384 * 768, 768, 544);
  transpose_cast_hl<<<dim3(6, 12), 256, 0, stream>>>(W_uq, WuqH, WuqL, 384, 768);
  transpose_cast_hl<<<dim3(8, 18), 256, 0, stream>>>(W_ukv, WukvH, WukvL, 512, 1152);

  // ---- phase A ----
  ln_hl<<<1024, 256, 0, stream>>>(x, 768, 768, ln1_w, nullptr, hH, hL, 768);
  gemm3<0><<<dim3(8, 32), 256, 0, stream>>>(hH, hL, 768, WcatH, WcatL, 768, Ccat, 928, nullptr, 4096, 928, 768);
  ln_qkv<<<2048, 256, 0, stream>>>(Ccat, q_ln_w, q_ln_b, kv_ln_w, kv_ln_b, cqH, cqL, kvlH, kvlL);
  gemm3<0><<<dim3(6, 32), 256, 0, stream>>>(cqH, cqL, 384, WuqH, WuqL, 384, Qf, 768, nullptr, 4096, 768, 384);
  gemm3<0><<<dim3(9, 32), 256, 0, stream>>>(kvlH, kvlL, 512, WukvH, WukvL, 512, KVf, 1152, nullptr, 4096, 1152, 512);
  build_qk<<<dim3(192, 2), 256, 0, stream>>>(Qf, KVf, Ccat, qbH, qbL, kbH, kbL);
  build_vt_hl<<<dim3(16, 48), 256, 0, stream>>>(KVf, vtH, vtL);
  attn3<<<dim3(8, 48), 256, 0, stream>>>(qbH, qbL, kbH, kbL, vtH, vtL, obH, obL);
  gemm3<1><<<dim3(6, 32), 256, 0, stream>>>(obH, obL, 768, WoH, WoL, 768, x2, 768, x, 4096, 768, 768);

  // ---- phase B ----
  ln_bf_f32<<<1024, 256, 0, stream>>>(x2, ln2_w, h2bf, h2f, out);
  route_score<<<1024, 256, 0, stream>>>(h2f, cent, rbias, topexp, gates);
  build_lists<<<8, 256, 0, stream>>>(topexp, counts, lists);

  // shared experts (concat): fc -> gelu -> actCat ; proj split-k3 (planes) + reduce
  cast_shared<<<9216, 256, 0, stream>>>((const float4*)s_fc, (const float4*)s_proj,
                                        (short4*)sfcCat, (short4*)sprojCat);
  gemm_fc<<<dim3(48, 32), 256, 0, stream>>>(h2bf, 768, sfcCat, 768, actCat, 6144, 768);
  gemm_sk<<<dim3(12, 32, 3), 256, 0, stream>>>(actCat, 6144, sprojCat, 6144, out, 768,
                                               skP1, skP2, 2048);
  sk_reduce<<<1536, 256, 0, stream>>>((float4*)out, (const float4*)skP1, (const float4*)skP2);

  // routed experts: all 8 at once, e = XCD, no atomics
  cast_bf<<<8192, 256, 0, stream>>>((const float4*)e_fc, (short4*)ewAll, 4718592);
  expert_fc_z<<<dim3(24, 32, 8), 256, 0, stream>>>(h2bf, ewAll, lists, counts, eact);
  cast_bf<<<8192, 256, 0, stream>>>((const float4*)e_proj, (short4*)ewAll, 4718592);
  expert_proj_one<<<dim3(12, 32, 8), 256, 0, stream>>>(eact, ewAll, lists, counts, routed);
  gather_routed<<<1536, 256, 0, stream>>>(routed, gates, out);
}